// Round 3
// baseline (10848.885 us; speedup 1.0000x reference)
//
#include <hip/hip_runtime.h>
#include <math.h>

#define BB 2
#define NSEQ 4096
#define N1 4097
#define NPAD 4352
#define PADR 255
#define DIM 512
#define NH 8
#define DH 64
#define LM 256
#define NT 1536

// ---------------- block reduce helpers (blockDim.x == 256) ----------------
__device__ __forceinline__ float blk_sum(float v, float* red){
  int t = threadIdx.x;
  red[t] = v; __syncthreads();
  for (int s = 128; s > 0; s >>= 1){ if (t < s) red[t] += red[t+s]; __syncthreads(); }
  float r = red[0]; __syncthreads(); return r;
}
__device__ __forceinline__ double blk_sumd(double v, double* red){
  int t = threadIdx.x;
  red[t] = v; __syncthreads();
  for (int s = 128; s > 0; s >>= 1){ if (t < s) red[t] += red[t+s]; __syncthreads(); }
  double r = red[0]; __syncthreads(); return r;
}
__device__ __forceinline__ double blk_maxd(double v, double* red){
  int t = threadIdx.x;
  red[t] = v; __syncthreads();
  for (int s = 128; s > 0; s >>= 1){ if (t < s) red[t] = fmax(red[t], red[t+s]); __syncthreads(); }
  double r = red[0]; __syncthreads(); return r;
}

// ---------------- generic fp32 GEMM: C = act(A @ W^T + bias + res) ----------------
__global__ __launch_bounds__(256) void gemm_f32(
    const float* __restrict__ A, const float* __restrict__ W,
    const float* __restrict__ bias, const float* __restrict__ res,
    float* __restrict__ C, int M, int N, int K, int act)
{
  __shared__ float As[32][33], Ws[32][33];
  int tx = threadIdx.x & 15, ty = threadIdx.x >> 4;
  int row0 = blockIdx.y * 32, col0 = blockIdx.x * 32;
  float acc00=0.f, acc01=0.f, acc10=0.f, acc11=0.f;
  for (int k0 = 0; k0 < K; k0 += 32) {
    for (int i = threadIdx.x; i < 1024; i += 256) {
      int r = i >> 5, c = i & 31;
      int gr = row0 + r;
      As[r][c] = (gr < M) ? A[(size_t)gr * K + k0 + c] : 0.f;
      int wr = col0 + r;
      Ws[r][c] = (wr < N) ? W[(size_t)wr * K + k0 + c] : 0.f;
    }
    __syncthreads();
    #pragma unroll
    for (int kk = 0; kk < 32; ++kk) {
      float a0 = As[ty*2][kk],   a1 = As[ty*2+1][kk];
      float w0 = Ws[tx*2][kk],   w1 = Ws[tx*2+1][kk];
      acc00 += a0*w0; acc01 += a0*w1; acc10 += a1*w0; acc11 += a1*w1;
    }
    __syncthreads();
  }
  float accv[2][2] = {{acc00, acc01},{acc10, acc11}};
  for (int a = 0; a < 2; ++a) for (int b = 0; b < 2; ++b) {
    int r = row0 + ty*2 + a, c = col0 + tx*2 + b;
    if (r < M && c < N) {
      float v = accv[a][b];
      if (bias) v += bias[c];
      if (res)  v += res[(size_t)r * N + c];
      if (act == 1) v = fmaxf(v, 0.f);
      else if (act == 2) v = (v >= 0.f) ? v : 0.01f * v;
      C[(size_t)r * N + c] = v;
    }
  }
}

// ---------------- fp64 batched 256x256x256: C = alpha*(A@B) + diag*I ----------------
__global__ __launch_bounds__(256) void mm_b_d(
    const double* __restrict__ A, const double* __restrict__ Bm, double* __restrict__ C,
    double alpha, double diag)
{
  int bh = blockIdx.z;
  const double* Ab = A + (size_t)bh * 65536;
  const double* Bb = Bm + (size_t)bh * 65536;
  double* Cb = C + (size_t)bh * 65536;
  __shared__ double As[32][33], Bs[32][33];
  int tx = threadIdx.x & 15, ty = threadIdx.x >> 4;
  int row0 = blockIdx.y * 32, col0 = blockIdx.x * 32;
  double acc00=0., acc01=0., acc10=0., acc11=0.;
  for (int k0 = 0; k0 < 256; k0 += 32) {
    for (int i = threadIdx.x; i < 1024; i += 256) {
      int r = i >> 5, c = i & 31;
      As[r][c] = Ab[(size_t)(row0 + r) * 256 + k0 + c];
      Bs[r][c] = Bb[(size_t)(k0 + r) * 256 + col0 + c];
    }
    __syncthreads();
    #pragma unroll
    for (int kk = 0; kk < 32; ++kk) {
      double a0 = As[ty*2][kk],  a1 = As[ty*2+1][kk];
      double b0 = Bs[kk][tx*2],  b1 = Bs[kk][tx*2+1];
      acc00 += a0*b0; acc01 += a0*b1; acc10 += a1*b0; acc11 += a1*b1;
    }
    __syncthreads();
  }
  double accv[2][2] = {{acc00,acc01},{acc10,acc11}};
  for (int a = 0; a < 2; ++a) for (int b = 0; b < 2; ++b) {
    int r = row0 + ty*2 + a, c = col0 + tx*2 + b;
    double v = alpha * accv[a][b];
    if (r == c) v += diag;
    Cb[(size_t)r * 256 + c] = v;
  }
}

// zav(f32) = zc(f64) @ av(f32), per bh: 256x64x256
__global__ __launch_bounds__(256) void mm_zav_d(const double* __restrict__ A,
                                                const float* __restrict__ B, float* __restrict__ C)
{
  int bh = blockIdx.z;
  const double* Ab = A + (size_t)bh * 65536;
  const float* Bb = B + (size_t)bh * 16384;
  float* Cb = C + (size_t)bh * 16384;
  __shared__ double As[32][33];
  __shared__ float  Bs[32][33];
  int tx = threadIdx.x & 15, ty = threadIdx.x >> 4;
  int row0 = blockIdx.y * 32, col0 = blockIdx.x * 32;
  double acc00=0., acc01=0., acc10=0., acc11=0.;
  for (int k0 = 0; k0 < 256; k0 += 32) {
    for (int i = threadIdx.x; i < 1024; i += 256) {
      int r = i >> 5, c = i & 31;
      As[r][c] = Ab[(size_t)(row0 + r) * 256 + k0 + c];
      Bs[r][c] = Bb[(size_t)(k0 + r) * 64 + col0 + c];
    }
    __syncthreads();
    #pragma unroll
    for (int kk = 0; kk < 32; ++kk) {
      double a0 = As[ty*2][kk],  a1 = As[ty*2+1][kk];
      double b0 = (double)Bs[kk][tx*2],  b1 = (double)Bs[kk][tx*2+1];
      acc00 += a0*b0; acc01 += a0*b1; acc10 += a1*b0; acc11 += a1*b1;
    }
    __syncthreads();
  }
  double accv[2][2] = {{acc00,acc01},{acc10,acc11}};
  for (int a = 0; a < 2; ++a) for (int b = 0; b < 2; ++b) {
    int r = row0 + ty*2 + a, c = col0 + tx*2 + b;
    Cb[(size_t)r * 64 + c] = (float)accv[a][b];
  }
}

// t1 = diag*I - src  (fp64, 16 x 256 x 256)
__global__ void ewise_diag_d(const double* __restrict__ src, double* __restrict__ dst, double diag){
  size_t idx = (size_t)blockIdx.x * 256 + threadIdx.x;
  int rc = (int)(idx & 65535);
  int r = rc >> 8, c = rc & 255;
  double v = -src[idx];
  if (r == c) v += diag;
  dst[idx] = v;
}

// ---------------- LN + front zero-pad into (B,NPAD,DIM) ----------------
__global__ __launch_bounds__(256) void ln_pad(const float* __restrict__ hsrc, float* __restrict__ dst,
                                              const float* __restrict__ g, const float* __restrict__ bt){
  __shared__ double red[256];
  int row = blockIdx.x;
  int b = row / NPAD, r = row % NPAD;
  float* drow = dst + (size_t)row * DIM;
  int t = threadIdx.x;
  if (r < PADR) { drow[t] = 0.f; drow[t + 256] = 0.f; return; }
  const float* x = hsrc + ((size_t)b * N1 + (r - PADR)) * DIM;
  double x0 = (double)x[t], x1 = (double)x[t + 256];
  double mu = blk_sumd(x0 + x1, red) * (1.0/512.0);
  double d0 = x0 - mu, d1 = x1 - mu;
  double var = blk_sumd(d0*d0 + d1*d1, red) * (1.0/512.0);
  double inv = 1.0 / sqrt(var + 1e-5);
  drow[t]       = (float)(d0 * inv * (double)g[t]       + (double)bt[t]);
  drow[t + 256] = (float)(d1 * inv * (double)g[t + 256] + (double)bt[t + 256]);
}

// ---------------- landmarks: ql (scaled by 1/8), kl ----------------
__global__ void landmark(const float* __restrict__ qkv, float* __restrict__ ql, float* __restrict__ kl){
  int blk = blockIdx.x;            // bh*256 + m
  int bh = blk >> 8, m = blk & 255;
  int b = bh >> 3, hh = bh & 7;
  int d = threadIdx.x;             // 64
  double sq = 0., sk = 0.;
  for (int l = 0; l < 17; ++l) {
    size_t o = ((size_t)b * NPAD + m * 17 + l) * NT + hh * 64 + d;
    sq += (double)qkv[o];
    sk += (double)qkv[o + 512];
  }
  ql[((size_t)bh * 256 + m) * 64 + d] = (float)(0.125 * sq / 17.0);
  kl[((size_t)bh * 256 + m) * 64 + d] = (float)(sk / 17.0);
}

// ---------------- a2 (fp64) = softmax(ql @ kl^T) ----------------
__global__ __launch_bounds__(256) void a2_kernel_d(const float* __restrict__ ql, const float* __restrict__ kl,
                                                   double* __restrict__ a2){
  __shared__ float qs[64]; __shared__ double red[256];
  int blk = blockIdx.x;            // bh*256 + i
  int bh = blk >> 8, i = blk & 255;
  int t = threadIdx.x;
  if (t < 64) qs[t] = ql[((size_t)bh * 256 + i) * 64 + t];
  __syncthreads();
  const float* kr = kl + ((size_t)bh * 256 + t) * 64;
  double s = 0.;
  #pragma unroll
  for (int q = 0; q < 64; ++q) s += (double)qs[q] * (double)kr[q];
  double mx = blk_maxd(s, red);
  double e = exp(s - mx);
  double sum = blk_sumd(e, red);
  a2[((size_t)bh * 256 + i) * 256 + t] = e / sum;
}

// per-(b,h) max colsum / rowsum (fp64)
__global__ __launch_bounds__(256) void colrow_max_d(const double* __restrict__ a2, double* __restrict__ scal){
  __shared__ double red[256];
  int bh = blockIdx.x, t = threadIdx.x;
  const double* A = a2 + (size_t)bh * 65536;
  double cs = 0., rs = 0.;
  for (int i = 0; i < 256; ++i) cs += A[(size_t)i * 256 + t];
  for (int j = 0; j < 256; ++j) rs += A[(size_t)t * 256 + j];
  double cmax = blk_maxd(cs, red);
  double rmax = blk_maxd(rs, red);
  if (t == 0) { scal[bh] = cmax; scal[16 + bh] = rmax; }
}
__global__ void scal_red_d(double* scal){
  if (threadIdx.x == 0) {
    double cm = scal[0], rm = scal[16];
    for (int i = 1; i < 16; ++i) { cm = fmax(cm, scal[i]); rm = fmax(rm, scal[16 + i]); }
    scal[32] = 1.0 / (rm * cm);
  }
}
// z0 = a2^T * invscale (fp64)
__global__ void z0_d(const double* __restrict__ a2, double* __restrict__ z, const double* __restrict__ scal){
  size_t idx = (size_t)blockIdx.x * 256 + threadIdx.x;
  size_t bh = idx >> 16;
  int rc = (int)(idx & 65535);
  int r = rc >> 8, c = rc & 255;
  z[idx] = a2[(bh << 16) + (size_t)c * 256 + r] * scal[32];
}

// ---------------- av = softmax(ql @ k^T) @ v   (fused a3 row, fp64 internals) ----------------
__global__ __launch_bounds__(256) void a3v_kernel(const float* __restrict__ qkv, const float* __restrict__ ql,
                                                  float* __restrict__ av){
  __shared__ float qs[64];
  __shared__ double sc[NPAD];
  __shared__ double red[256];
  int blk = blockIdx.x; int bh = blk >> 8, m = blk & 255;
  int b = bh >> 3, hh = bh & 7;
  int t = threadIdx.x;
  if (t < 64) qs[t] = ql[((size_t)bh * 256 + m) * 64 + t];
  __syncthreads();
  double lmax = -1e300;
  for (int n = t; n < NPAD; n += 256) {
    const float* kr = qkv + ((size_t)b * NPAD + n) * NT + 512 + hh * 64;
    double s = 0.;
    #pragma unroll
    for (int q = 0; q < 64; ++q) s += (double)qs[q] * (double)kr[q];
    sc[n] = s; lmax = fmax(lmax, s);
  }
  double mx = blk_maxd(lmax, red);
  double lsum = 0.;
  for (int n = t; n < NPAD; n += 256) { double e = exp(sc[n] - mx); sc[n] = e; lsum += e; }
  double denom = blk_sumd(lsum, red);
  __syncthreads();
  int d = t & 63, ch = t >> 6;
  double p = 0.;
  for (int n = ch; n < NPAD; n += 4)
    p += sc[n] * (double)qkv[((size_t)b * NPAD + n) * NT + 1024 + hh * 64 + d];
  red[t] = p; __syncthreads();
  if (ch == 0) {
    double tot = red[d] + red[64 + d] + red[128 + d] + red[192 + d];
    av[((size_t)bh * 256 + m) * 64 + d] = (float)(tot / denom);
  }
}

// ---------------- depthwise 33x1 residual conv on v -> merged ----------------
__global__ __launch_bounds__(256) void conv_res(const float* __restrict__ qkv, const float* __restrict__ rk,
                                                float* __restrict__ merged){
  __shared__ float rks[264];
  int t = threadIdx.x;
  for (int i = t; i < 264; i += 256) rks[i] = rk[i];   // FIX: full coverage (264 > blockDim)
  __syncthreads();
  size_t idx = (size_t)blockIdx.x * 256 + t;
  int c = (int)(idx & 511);
  int n = (int)((idx >> 9) % NPAD);
  int b = (int)(idx / ((size_t)512 * NPAD));
  int hh = c >> 6;
  float acc = 0.f;
  #pragma unroll
  for (int kk = 0; kk < 33; ++kk) {
    int nn = n + kk - 16;
    if (nn >= 0 && nn < NPAD)
      acc += rks[hh * 33 + kk] * qkv[((size_t)b * NPAD + nn) * NT + 1024 + c];
  }
  merged[((size_t)b * NPAD + n) * DIM + c] = acc;
}

// ---------------- merged += softmax(q @ kl^T) @ zav (fp64 internals) ----------------
__global__ __launch_bounds__(256) void a1_out(const float* __restrict__ qkv, const float* __restrict__ kl,
                                              const float* __restrict__ zav, float* __restrict__ merged){
  __shared__ float qs[64]; __shared__ double sc[256]; __shared__ double red[256];
  int blk = blockIdx.x;            // bh*NPAD + n
  int n = blk % NPAD; int bh = blk / NPAD; int b = bh >> 3, hh = bh & 7;
  int t = threadIdx.x;
  if (t < 64) qs[t] = 0.125f * qkv[((size_t)b * NPAD + n) * NT + hh * 64 + t];
  __syncthreads();
  const float* kr = kl + ((size_t)bh * 256 + t) * 64;
  double s = 0.;
  #pragma unroll
  for (int q = 0; q < 64; ++q) s += (double)qs[q] * (double)kr[q];
  double mx = blk_maxd(s, red);
  double e = exp(s - mx);
  double denom = blk_sumd(e, red);
  sc[t] = e; __syncthreads();
  int d = t & 63, ch = t >> 6;
  double p = 0.;
  for (int m = ch; m < 256; m += 4) p += sc[m] * (double)zav[((size_t)bh * 256 + m) * 64 + d];
  red[t] = p; __syncthreads();
  if (ch == 0) {
    double tot = red[d] + red[64 + d] + red[128 + d] + red[192 + d];
    merged[((size_t)b * NPAD + n) * DIM + hh * 64 + d] += (float)(tot / denom);
  }
}

// ---------------- PPEG depthwise convs ----------------
__global__ __launch_bounds__(256) void dwconv(const float* __restrict__ hsrc,
    const float* __restrict__ w7, const float* __restrict__ b7,
    const float* __restrict__ w5, const float* __restrict__ b5,
    const float* __restrict__ w3, const float* __restrict__ b3,
    float* __restrict__ hdst){
  size_t idx = (size_t)blockIdx.x * 256 + threadIdx.x;
  int c = (int)(idx & 511);
  int sp = (int)((idx >> 9) & 4095);
  int b = (int)(idx >> 21);
  int y = sp >> 6, x = sp & 63;
  const float* fb = hsrc + ((size_t)b * N1 + 1) * DIM + c;
  float acc = fb[(size_t)sp * DIM] + b7[c] + b5[c] + b3[c];
  for (int ky = 0; ky < 7; ++ky) { int yy = y + ky - 3; if (yy < 0 || yy >= 64) continue;
    for (int kx = 0; kx < 7; ++kx) { int xx = x + kx - 3; if (xx < 0 || xx >= 64) continue;
      acc += w7[(size_t)c * 49 + ky * 7 + kx] * fb[(size_t)(yy * 64 + xx) * DIM]; } }
  for (int ky = 0; ky < 5; ++ky) { int yy = y + ky - 2; if (yy < 0 || yy >= 64) continue;
    for (int kx = 0; kx < 5; ++kx) { int xx = x + kx - 2; if (xx < 0 || xx >= 64) continue;
      acc += w5[(size_t)c * 25 + ky * 5 + kx] * fb[(size_t)(yy * 64 + xx) * DIM]; } }
  for (int ky = 0; ky < 3; ++ky) { int yy = y + ky - 1; if (yy < 0 || yy >= 64) continue;
    for (int kx = 0; kx < 3; ++kx) { int xx = x + kx - 1; if (xx < 0 || xx >= 64) continue;
      acc += w3[(size_t)c * 9 + ky * 3 + kx] * fb[(size_t)(yy * 64 + xx) * DIM]; } }
  hdst[((size_t)b * N1 + 1 + sp) * DIM + c] = acc;
}

__global__ void set_cls(float* h, const float* cls){
  int t = threadIdx.x;
  if (t < 1024) { int b = t >> 9, c = t & 511; h[(size_t)b * N1 * DIM + c] = cls[c]; }
}
__global__ void copy_cls(float* dst, const float* src){
  int t = threadIdx.x;
  if (t < 1024) { int b = t >> 9, c = t & 511; dst[(size_t)b * N1 * DIM + c] = src[(size_t)b * N1 * DIM + c]; }
}

__global__ __launch_bounds__(256) void final_ln(const float* __restrict__ h2, const float* __restrict__ g,
                                                const float* __restrict__ bt, float* __restrict__ hcls){
  __shared__ double red[256];
  int b = blockIdx.x, t = threadIdx.x;
  const float* x = h2 + (size_t)b * N1 * DIM;
  double x0 = (double)x[t], x1 = (double)x[t + 256];
  double mu = blk_sumd(x0 + x1, red) * (1.0/512.0);
  double d0 = x0 - mu, d1 = x1 - mu;
  double var = blk_sumd(d0*d0 + d1*d1, red) * (1.0/512.0);
  double inv = 1.0 / sqrt(var + 1e-5);
  hcls[b * 512 + t]       = (float)(d0 * inv * (double)g[t]       + (double)bt[t]);
  hcls[b * 512 + t + 256] = (float)(d1 * inv * (double)g[t + 256] + (double)bt[t + 256]);
}

__global__ void build_xc(const float* __restrict__ hcls, const float* __restrict__ reh, float* __restrict__ xc){
  size_t idx = (size_t)blockIdx.x * 256 + threadIdx.x;
  int row = (int)(idx >> 9), c = (int)(idx & 511);
  xc[idx] = (row < 2) ? hcls[row * 512 + c] : reh[(size_t)(row - 2) * 512 + c];
}

__global__ __launch_bounds__(256) void norms_k(const float* __restrict__ xg, double* __restrict__ rn){
  __shared__ double red[256];
  int i = blockIdx.x, t = threadIdx.x;
  double a = (double)xg[(size_t)i * 512 + t], b = (double)xg[(size_t)i * 512 + t + 256];
  double s = blk_sumd(a*a + b*b, red);
  if (t == 0) rn[i] = sqrt(s);
}

__global__ __launch_bounds__(256) void topk_k(const float* __restrict__ xg, const double* __restrict__ rn,
                                              int* __restrict__ idxb){
  __shared__ double sc[256]; __shared__ double redv[256]; __shared__ int redi[256];
  int i = blockIdx.x, j = threadIdx.x;
  const float* xi = xg + (size_t)i * 512;
  const float* xj = xg + (size_t)j * 512;
  double s = 0.;
  for (int c = 0; c < 512; ++c) s += (double)xi[c] * (double)xj[c];
  s /= (rn[i] * rn[j]);
  sc[j] = s; __syncthreads();
  for (int r = 0; r < 4; ++r) {
    redv[j] = sc[j]; redi[j] = j; __syncthreads();
    for (int st = 128; st > 0; st >>= 1) {
      if (j < st) {
        if (redv[j + st] > redv[j] || (redv[j + st] == redv[j] && redi[j + st] < redi[j])) {
          redv[j] = redv[j + st]; redi[j] = redi[j + st];
        }
      }
      __syncthreads();
    }
    if (j == 0) { idxb[i * 4 + r] = redi[0]; sc[redi[0]] = -1e300; }
    __syncthreads();
  }
}

__global__ void edge_k(const float* __restrict__ xg, const int* __restrict__ idxb, float* __restrict__ edge){
  size_t idx = (size_t)blockIdx.x * 256 + threadIdx.x;
  int i = (int)(idx >> 9), c = (int)(idx & 511);
  const int* id = idxb + i * 4;
  edge[idx] = 0.25f * (xg[(size_t)id[0]*512 + c] + xg[(size_t)id[1]*512 + c] +
                       xg[(size_t)id[2]*512 + c] + xg[(size_t)id[3]*512 + c]);
}
__global__ void h1gather_k(const float* __restrict__ h1, const int* __restrict__ idxb, float* __restrict__ out){
  size_t idx = (size_t)blockIdx.x * 256 + threadIdx.x;
  int i = (int)(idx >> 9), c = (int)(idx & 511);
  const int* id = idxb + i * 4;
  out[idx] = h1[idx] + 0.25f * (h1[(size_t)id[0]*512 + c] + h1[(size_t)id[1]*512 + c] +
                                h1[(size_t)id[2]*512 + c] + h1[(size_t)id[3]*512 + c]);
}
__global__ void vadd_k(const float* __restrict__ a, const float* __restrict__ b, float* __restrict__ c){
  size_t idx = (size_t)blockIdx.x * 256 + threadIdx.x;
  c[idx] = a[idx] + b[idx];
}

__global__ void logits2(const float* __restrict__ src, const float* __restrict__ w,
                        const float* __restrict__ bias, float* __restrict__ out){
  int rc = blockIdx.x; int r = rc >> 1, c = rc & 1;
  int t = threadIdx.x; // 64
  double s = 0.;
  for (int k = t; k < 512; k += 64) s += (double)src[(size_t)r * 512 + k] * (double)w[(size_t)c * 512 + k];
  for (int off = 32; off > 0; off >>= 1) s += __shfl_down(s, off);
  if (t == 0) out[rc] = (float)(s + (double)bias[c]);
}

__global__ void sentinel_k(float* out){ if (threadIdx.x < 12) out[threadIdx.x] = 1e30f; }

// ---------------- host-side nystrom block ----------------
struct NysBufs {
  float *pad, *qkv, *ql, *kl, *av, *zav, *merged;
  double *a2d, *azd, *t1d, *t2d, *zAd, *zBd, *scald;
};

static void run_nystrom(hipStream_t stream, float* hbuf,
                        const float* lng, const float* lnb, const float* qkvw,
                        const float* outw, const float* outb, const float* rk,
                        const NysBufs& w)
{
  ln_pad<<<BB * NPAD, 256, 0, stream>>>(hbuf, w.pad, lng, lnb);
  gemm_f32<<<dim3(NT/32, (BB*NPAD)/32), 256, 0, stream>>>(w.pad, qkvw, nullptr, nullptr, w.qkv,
                                                          BB*NPAD, NT, DIM, 0);
  // pad is dead from here on within this call; a2d/azd overlay its storage.
  landmark<<<BB * NH * LM, 64, 0, stream>>>(w.qkv, w.ql, w.kl);
  a2_kernel_d<<<BB * NH * LM, 256, 0, stream>>>(w.ql, w.kl, w.a2d);
  colrow_max_d<<<16, 256, 0, stream>>>(w.a2d, w.scald);
  scal_red_d<<<1, 64, 0, stream>>>(w.scald);
  z0_d<<<4096, 256, 0, stream>>>(w.a2d, w.zAd, w.scald);
  double* zc = w.zAd; double* zn = w.zBd;
  for (int it = 0; it < 6; ++it) {
    mm_b_d<<<dim3(8,8,16), 256, 0, stream>>>(w.a2d, zc, w.azd, 1.0, 0.0);
    ewise_diag_d<<<4096, 256, 0, stream>>>(w.azd, w.t1d, 7.0);
    mm_b_d<<<dim3(8,8,16), 256, 0, stream>>>(w.azd, w.t1d, w.t2d, -1.0, 15.0);
    mm_b_d<<<dim3(8,8,16), 256, 0, stream>>>(w.azd, w.t2d, w.t1d, -1.0, 13.0);
    mm_b_d<<<dim3(8,8,16), 256, 0, stream>>>(zc, w.t1d, zn, 0.25, 0.0);
    double* tmp = zc; zc = zn; zn = tmp;
  }
  a3v_kernel<<<BB * NH * LM, 256, 0, stream>>>(w.qkv, w.ql, w.av);
  mm_zav_d<<<dim3(2,8,16), 256, 0, stream>>>(zc, w.av, w.zav);
  // t1d/t2d are dead from here; conv_res overwrites their storage (merged).
  conv_res<<<(BB * NPAD * DIM) / 256, 256, 0, stream>>>(w.qkv, rk, w.merged);
  a1_out<<<BB * NH * NPAD, 256, 0, stream>>>(w.qkv, w.kl, w.zav, w.merged);
  for (int b = 0; b < BB; ++b)
    gemm_f32<<<dim3(DIM/32, (N1+31)/32), 256, 0, stream>>>(w.merged + ((size_t)b*NPAD + PADR)*DIM,
                                                           outw, outb,
                                                           hbuf + (size_t)b*N1*DIM,
                                                           hbuf + (size_t)b*N1*DIM,
                                                           N1, DIM, DIM, 0);
}

extern "C" void kernel_launch(void* const* d_in, const int* in_sizes, int n_in,
                              void* d_out, int out_size, void* d_ws, size_t ws_size,
                              hipStream_t stream) {
  (void)in_sizes; (void)n_in; (void)out_size;
  const float* x        = (const float*)d_in[0];
  const float* fc1_w    = (const float*)d_in[1];
  const float* fc1_b    = (const float*)d_in[2];
  const float* cls_tok  = (const float*)d_in[3];
  const float* ln1_g    = (const float*)d_in[4];
  const float* ln1_b    = (const float*)d_in[5];
  const float* qkv1_w   = (const float*)d_in[6];
  const float* out1_w   = (const float*)d_in[7];
  const float* out1_b   = (const float*)d_in[8];
  const float* res1_k   = (const float*)d_in[9];
  const float* ppeg_w7  = (const float*)d_in[10];
  const float* ppeg_b7  = (const float*)d_in[11];
  const float* ppeg_w5  = (const float*)d_in[12];
  const float* ppeg_b5  = (const float*)d_in[13];
  const float* ppeg_w3  = (const float*)d_in[14];
  const float* ppeg_b3  = (const float*)d_in[15];
  const float* ln2_g    = (const float*)d_in[16];
  const float* ln2_b    = (const float*)d_in[17];
  const float* qkv2_w   = (const float*)d_in[18];
  const float* out2_w   = (const float*)d_in[19];
  const float* out2_b   = (const float*)d_in[20];
  const float* res2_k   = (const float*)d_in[21];
  const float* norm_g   = (const float*)d_in[22];
  const float* norm_b   = (const float*)d_in[23];
  const float* fc2_w    = (const float*)d_in[24];
  const float* fc2_b    = (const float*)d_in[25];
  const float* dsl_w1   = (const float*)d_in[26];
  const float* dsl_b1   = (const float*)d_in[27];
  const float* dsl_w2   = (const float*)d_in[28];
  const float* dsl_b2   = (const float*)d_in[29];
  const float* gcn_w1   = (const float*)d_in[30];
  const float* gcn_we   = (const float*)d_in[31];
  const float* gcn_b1   = (const float*)d_in[32];
  const float* gcn_w2   = (const float*)d_in[33];
  const float* gcn_b2   = (const float*)d_in[34];
  const float* gcn_hw   = (const float*)d_in[35];
  const float* gcn_hb   = (const float*)d_in[36];
  const float* gcn_dw   = (const float*)d_in[37];
  const float* gcn_db   = (const float*)d_in[38];
  const float* rehearsal= (const float*)d_in[39];
  float* out = (float*)d_out;

  char* base = (char*)d_ws;
  size_t off = 0;
  auto takeb = [&](size_t bytes) { void* p = base + off; off += (bytes + 255) & ~(size_t)255; return p; };

  float* h    = (float*)takeb((size_t)BB * N1 * DIM * 4);
  float* h2   = (float*)takeb((size_t)BB * N1 * DIM * 4);
  NysBufs nb;
  nb.pad    = (float*)takeb((size_t)BB * NPAD * DIM * 4);     // 17.8 MB; a2d+azd overlay
  nb.qkv    = (float*)takeb((size_t)BB * NPAD * NT * 4);
  nb.ql     = (float*)takeb((size_t)BB * NH * LM * DH * 4);
  nb.kl     = (float*)takeb((size_t)BB * NH * LM * DH * 4);
  nb.av     = (float*)takeb((size_t)BB * NH * LM * DH * 4);
  nb.zav    = (float*)takeb((size_t)BB * NH * LM * DH * 4);
  nb.merged = (float*)takeb((size_t)BB * NPAD * DIM * 4);     // 17.8 MB; t1d+t2d overlay
  nb.zAd    = (double*)takeb((size_t)16 * 65536 * 8);
  nb.zBd    = (double*)takeb((size_t)16 * 65536 * 8);
  nb.scald  = (double*)takeb(64 * 8);
  float* hcls = (float*)takeb((size_t)BB * DIM * 4);
  float* xc   = (float*)takeb((size_t)256 * 512 * 4);
  float* xg1  = (float*)takeb((size_t)256 * 256 * 4);
  float* xg   = (float*)takeb((size_t)256 * 512 * 4);
  double* rn  = (double*)takeb(256 * 8);
  int*   idxb = (int*)takeb(1024 * 4);
  float* edge = (float*)takeb((size_t)256 * 512 * 4);
  float* h1g  = (float*)takeb((size_t)256 * 512 * 4);
  float* h1pn = (float*)takeb((size_t)256 * 512 * 4);
  float* h2g  = (float*)takeb((size_t)256 * 512 * 4);

  // fp64 overlays on dead fp32 regions (stream-ordered liveness verified):
  nb.a2d = (double*)nb.pad;                                    // 8 MB
  nb.azd = (double*)((char*)nb.pad + (size_t)16 * 65536 * 8);  // next 8 MB (pad is 17.8 MB)
  nb.t1d = (double*)nb.merged;
  nb.t2d = (double*)((char*)nb.merged + (size_t)16 * 65536 * 8);

  if (ws_size < off) { sentinel_k<<<1, 64, 0, stream>>>(out); return; }

  // --- stage A: fc1 + cls ---
  set_cls<<<1, 1024, 0, stream>>>(h, cls_tok);
  for (int b = 0; b < BB; ++b)
    gemm_f32<<<dim3(DIM/32, NSEQ/32), 256, 0, stream>>>(x + (size_t)b*NSEQ*DIM, fc1_w, fc1_b, nullptr,
                                                        h + ((size_t)b*N1 + 1)*DIM, NSEQ, DIM, DIM, 1);
  // --- nystrom block 1 (residual into h) ---
  run_nystrom(stream, h, ln1_g, ln1_b, qkv1_w, out1_w, out1_b, res1_k, nb);

  // --- PPEG: h2 = [cls, cnn + dw7 + dw5 + dw3] ---
  copy_cls<<<1, 1024, 0, stream>>>(h2, h);
  dwconv<<<(BB * NSEQ * DIM) / 256, 256, 0, stream>>>(h, ppeg_w7, ppeg_b7, ppeg_w5, ppeg_b5,
                                                      ppeg_w3, ppeg_b3, h2);
  // --- nystrom block 2 (residual into h2) ---
  run_nystrom(stream, h2, ln2_g, ln2_b, qkv2_w, out2_w, out2_b, res2_k, nb);

  // --- final LN (row 0) + heads ---
  final_ln<<<BB, 256, 0, stream>>>(h2, norm_g, norm_b, hcls);
  logits2<<<4, 64, 0, stream>>>(hcls, fc2_w, fc2_b, out + 0);

  // --- GCN branch ---
  build_xc<<<512, 256, 0, stream>>>(hcls, rehearsal, xc);
  gemm_f32<<<dim3(256/32, 256/32), 256, 0, stream>>>(xc, dsl_w1, dsl_b1, nullptr, xg1, 256, 256, 512, 2);
  gemm_f32<<<dim3(512/32, 256/32), 256, 0, stream>>>(xg1, dsl_w2, dsl_b2, nullptr, xg, 256, 512, 256, 2);
  norms_k<<<256, 256, 0, stream>>>(xg, rn);
  topk_k<<<256, 256, 0, stream>>>(xg, rn, idxb);
  edge_k<<<512, 256, 0, stream>>>(xg, idxb, edge);
  vadd_k<<<512, 256, 0, stream>>>(xg, edge, h1pn);     // h1pn temp = xg + edge
  gemm_f32<<<dim3(512/32, 256/32), 256, 0, stream>>>(h1pn, gcn_w1, nullptr, nullptr, h1g, 256, 512, 512, 0);
  gemm_f32<<<dim3(512/32, 256/32), 256, 0, stream>>>(edge, gcn_we, gcn_b1, h1g, h1g, 256, 512, 512, 1);
  h1gather_k<<<512, 256, 0, stream>>>(h1g, idxb, h1pn);
  gemm_f32<<<dim3(512/32, 256/32), 256, 0, stream>>>(h1pn, gcn_w2, gcn_b2, nullptr, h2g, 256, 512, 512, 0);
  logits2<<<4, 64, 0, stream>>>(h2g, gcn_hw, gcn_hb, out + 4);
  logits2<<<4, 64, 0, stream>>>(h1g, gcn_dw, gcn_db, out + 8);
}

// Round 4
// 7547.313 us; speedup vs baseline: 1.4375x; 1.4375x over previous
//
#include <hip/hip_runtime.h>
#include <math.h>

#define BB 2
#define NSEQ 4096
#define N1 4097
#define NPAD 4352
#define PADR 255
#define DIM 512
#define NH 8
#define DH 64
#define LM 256
#define NT 1536

// ---------------- block reduce helpers (blockDim.x == 256) ----------------
__device__ __forceinline__ float blk_sum(float v, float* red){
  int t = threadIdx.x;
  red[t] = v; __syncthreads();
  for (int s = 128; s > 0; s >>= 1){ if (t < s) red[t] += red[t+s]; __syncthreads(); }
  float r = red[0]; __syncthreads(); return r;
}
__device__ __forceinline__ float blk_max(float v, float* red){
  int t = threadIdx.x;
  red[t] = v; __syncthreads();
  for (int s = 128; s > 0; s >>= 1){ if (t < s) red[t] = fmaxf(red[t], red[t+s]); __syncthreads(); }
  float r = red[0]; __syncthreads(); return r;
}
__device__ __forceinline__ double blk_sumd(double v, double* red){
  int t = threadIdx.x;
  red[t] = v; __syncthreads();
  for (int s = 128; s > 0; s >>= 1){ if (t < s) red[t] += red[t+s]; __syncthreads(); }
  double r = red[0]; __syncthreads(); return r;
}

// ---------------- fp32 GEMM 64x64 tile, 4x4/thread: C = act(A @ W^T + bias + res) ----------------
__global__ __launch_bounds__(256) void gemm_f32(
    const float* __restrict__ A, const float* __restrict__ W,
    const float* __restrict__ bias, const float* __restrict__ res,
    float* __restrict__ C, int M, int N, int K, int act)
{
  __shared__ float As[64][33], Ws[64][33];
  int t = threadIdx.x;
  int tx = t & 15, ty = t >> 4;
  int row0 = blockIdx.y * 64, col0 = blockIdx.x * 64;
  float acc[4][4] = {};
  for (int k0 = 0; k0 < K; k0 += 32) {
    for (int i = t; i < 512; i += 256) {
      int r = i >> 3, c4 = (i & 7) << 2;
      int gr = row0 + r;
      float4 va = make_float4(0.f,0.f,0.f,0.f);
      if (gr < M) va = *(const float4*)&A[(size_t)gr * K + k0 + c4];
      As[r][c4] = va.x; As[r][c4+1] = va.y; As[r][c4+2] = va.z; As[r][c4+3] = va.w;
      int wr = col0 + r;
      float4 vw = make_float4(0.f,0.f,0.f,0.f);
      if (wr < N) vw = *(const float4*)&W[(size_t)wr * K + k0 + c4];
      Ws[r][c4] = vw.x; Ws[r][c4+1] = vw.y; Ws[r][c4+2] = vw.z; Ws[r][c4+3] = vw.w;
    }
    __syncthreads();
    #pragma unroll
    for (int kk = 0; kk < 32; ++kk) {
      float a[4], w[4];
      #pragma unroll
      for (int i = 0; i < 4; ++i) { a[i] = As[ty*4+i][kk]; w[i] = Ws[tx*4+i][kk]; }
      #pragma unroll
      for (int i = 0; i < 4; ++i)
        #pragma unroll
        for (int j = 0; j < 4; ++j) acc[i][j] += a[i]*w[j];
    }
    __syncthreads();
  }
  for (int i = 0; i < 4; ++i) for (int j = 0; j < 4; ++j) {
    int r = row0 + ty*4 + i, c = col0 + tx*4 + j;
    if (r < M && c < N) {
      float v = acc[i][j];
      if (bias) v += bias[c];
      if (res)  v += res[(size_t)r * N + c];
      if (act == 1) v = fmaxf(v, 0.f);
      else if (act == 2) v = (v >= 0.f) ? v : 0.01f * v;
      C[(size_t)r * N + c] = v;
    }
  }
}

// ---------------- fp32 batched (16x) GEMM 32x64 tile: C = alpha*(A@B)+diag*I, opt D = diag2*I - C ----------------
// A: 256x256 per bh; B: 256xN per bh (N = 256 or 64)
__global__ __launch_bounds__(256) void mm_bf(
    const float* __restrict__ A, const float* __restrict__ Bm,
    float* __restrict__ C, float* __restrict__ D,
    int N, float alpha, float diag, float diag2)
{
  int bh = blockIdx.z;
  const float* Ab = A + (size_t)bh * 65536;
  const float* Bb = Bm + (size_t)bh * 256 * N;
  float* Cb = C + (size_t)bh * 256 * N;
  float* Db = D ? (D + (size_t)bh * 256 * N) : (float*)0;
  __shared__ float As[32][33], Bs[32][68];
  int t = threadIdx.x;
  int tx = t & 15, ty = t >> 4;
  int row0 = blockIdx.y * 32, col0 = blockIdx.x * 64;
  float acc[2][4] = {};
  for (int k0 = 0; k0 < 256; k0 += 32) {
    { int r = t >> 3, c4 = (t & 7) << 2;
      float4 v = *(const float4*)&Ab[(size_t)(row0 + r) * 256 + k0 + c4];
      As[r][c4] = v.x; As[r][c4+1] = v.y; As[r][c4+2] = v.z; As[r][c4+3] = v.w; }
    for (int i = t; i < 512; i += 256) {
      int r = i >> 4, c4 = (i & 15) << 2;
      float4 v = *(const float4*)&Bb[(size_t)(k0 + r) * N + col0 + c4];
      *(float4*)&Bs[r][c4] = v;
    }
    __syncthreads();
    #pragma unroll
    for (int kk = 0; kk < 32; ++kk) {
      float a0 = As[ty*2][kk], a1 = As[ty*2+1][kk];
      float4 b = *(const float4*)&Bs[kk][tx*4];
      acc[0][0] += a0*b.x; acc[0][1] += a0*b.y; acc[0][2] += a0*b.z; acc[0][3] += a0*b.w;
      acc[1][0] += a1*b.x; acc[1][1] += a1*b.y; acc[1][2] += a1*b.z; acc[1][3] += a1*b.w;
    }
    __syncthreads();
  }
  #pragma unroll
  for (int i = 0; i < 2; ++i)
    #pragma unroll
    for (int j = 0; j < 4; ++j) {
      int r = row0 + ty*2 + i, c = col0 + tx*4 + j;
      float v = alpha * acc[i][j];
      if (r == c) v += diag;
      Cb[(size_t)r * N + c] = v;
      if (Db) Db[(size_t)r * N + c] = ((r == c) ? diag2 : 0.f) - v;
    }
}

// ---------------- LN + front zero-pad into (B,NPAD,DIM) ----------------
__global__ __launch_bounds__(256) void ln_pad(const float* __restrict__ hsrc, float* __restrict__ dst,
                                              const float* __restrict__ g, const float* __restrict__ bt){
  __shared__ double red[256];
  int row = blockIdx.x;
  int b = row / NPAD, r = row % NPAD;
  float* drow = dst + (size_t)row * DIM;
  int t = threadIdx.x;
  if (r < PADR) { drow[t] = 0.f; drow[t + 256] = 0.f; return; }
  const float* x = hsrc + ((size_t)b * N1 + (r - PADR)) * DIM;
  double x0 = (double)x[t], x1 = (double)x[t + 256];
  double mu = blk_sumd(x0 + x1, red) * (1.0/512.0);
  double d0 = x0 - mu, d1 = x1 - mu;
  double var = blk_sumd(d0*d0 + d1*d1, red) * (1.0/512.0);
  double inv = 1.0 / sqrt(var + 1e-5);
  drow[t]       = (float)(d0 * inv * (double)g[t]       + (double)bt[t]);
  drow[t + 256] = (float)(d1 * inv * (double)g[t + 256] + (double)bt[t + 256]);
}

// ---------------- landmarks: ql (scaled by 1/8), kl ----------------
__global__ void landmark(const float* __restrict__ qkv, float* __restrict__ ql, float* __restrict__ kl){
  int blk = blockIdx.x;            // bh*256 + m
  int bh = blk >> 8, m = blk & 255;
  int b = bh >> 3, hh = bh & 7;
  int d = threadIdx.x;             // 64
  float sq = 0.f, sk = 0.f;
  for (int l = 0; l < 17; ++l) {
    size_t o = ((size_t)b * NPAD + m * 17 + l) * NT + hh * 64 + d;
    sq += qkv[o];
    sk += qkv[o + 512];
  }
  ql[((size_t)bh * 256 + m) * 64 + d] = 0.125f * sq / 17.f;
  kl[((size_t)bh * 256 + m) * 64 + d] = sk / 17.f;
}

// ---------------- tiled transposes ----------------
// kT[bh][d][n] = qkv.K[b][n][hh*64+d]; grid (NPAD/64, 16)
__global__ __launch_bounds__(256) void transpose_k(const float* __restrict__ qkv, float* __restrict__ kT){
  __shared__ float tile[64][65];
  int bh = blockIdx.y;
  int n0 = blockIdx.x * 64;
  int b = bh >> 3, hh = bh & 7;
  int t = threadIdx.x;
  for (int i = t; i < 4096; i += 256) {
    int r = i >> 6, c = i & 63;
    tile[r][c] = qkv[((size_t)b * NPAD + n0 + r) * NT + 512 + hh * 64 + c];
  }
  __syncthreads();
  float* kb = kT + (size_t)bh * 64 * NPAD;
  for (int i = t; i < 4096; i += 256) {
    int d = i >> 6, nn = i & 63;
    kb[(size_t)d * NPAD + n0 + nn] = tile[nn][d];
  }
}
// klT[bh][d][m] = kl[bh][m][d]; grid (LM/64, 16)
__global__ __launch_bounds__(256) void transpose_kl(const float* __restrict__ kl, float* __restrict__ klT){
  __shared__ float tile[64][65];
  int bh = blockIdx.y;
  int m0 = blockIdx.x * 64;
  int t = threadIdx.x;
  for (int i = t; i < 4096; i += 256) {
    int r = i >> 6, c = i & 63;
    tile[r][c] = kl[((size_t)bh * 256 + m0 + r) * 64 + c];
  }
  __syncthreads();
  float* kb = klT + (size_t)bh * 64 * 256;
  for (int i = t; i < 4096; i += 256) {
    int d = i >> 6, mm = i & 63;
    kb[(size_t)d * 256 + m0 + mm] = tile[mm][d];
  }
}

// ---------------- a2 = softmax(ql @ kl^T) (fp32, coalesced via klT) ----------------
__global__ __launch_bounds__(256) void a2_kernel(const float* __restrict__ ql, const float* __restrict__ klT,
                                                 float* __restrict__ a2){
  __shared__ float qs[64]; __shared__ float red[256];
  int blk = blockIdx.x;            // bh*256 + i
  int bh = blk >> 8, i = blk & 255;
  int t = threadIdx.x;
  if (t < 64) qs[t] = ql[((size_t)bh * 256 + i) * 64 + t];
  __syncthreads();
  const float* kb = klT + (size_t)bh * 16384;
  float s = 0.f;
  #pragma unroll
  for (int d = 0; d < 64; ++d) s += qs[d] * kb[d * 256 + t];
  float mx = blk_max(s, red);
  float e = expf(s - mx);
  float sum = blk_sum(e, red);
  a2[((size_t)bh * 256 + i) * 256 + t] = e / sum;
}

// per-(b,h) max colsum / rowsum (fp32)
__global__ __launch_bounds__(256) void colrow_max(const float* __restrict__ a2, float* __restrict__ scal){
  __shared__ float red[256];
  int bh = blockIdx.x, t = threadIdx.x;
  const float* A = a2 + (size_t)bh * 65536;
  float cs = 0.f, rs = 0.f;
  for (int i = 0; i < 256; ++i) cs += A[(size_t)i * 256 + t];
  for (int j = 0; j < 256; ++j) rs += A[(size_t)t * 256 + j];
  float cmax = blk_max(cs, red);
  float rmax = blk_max(rs, red);
  if (t == 0) { scal[bh] = cmax; scal[16 + bh] = rmax; }
}
__global__ void scal_red(float* scal){
  if (threadIdx.x == 0) {
    float cm = scal[0], rm = scal[16];
    for (int i = 1; i < 16; ++i) { cm = fmaxf(cm, scal[i]); rm = fmaxf(rm, scal[16 + i]); }
    scal[32] = 1.f / (rm * cm);
  }
}
// z0 = a2^T * invscale
__global__ void z0_kernel(const float* __restrict__ a2, float* __restrict__ z, const float* __restrict__ scal){
  size_t idx = (size_t)blockIdx.x * 256 + threadIdx.x;
  size_t bh = idx >> 16;
  int rc = (int)(idx & 65535);
  int r = rc >> 8, c = rc & 255;
  z[idx] = a2[(bh << 16) + (size_t)c * 256 + r] * scal[32];
}

// ---------------- av = softmax(ql @ k^T) @ v  (fp32, coalesced via kT) ----------------
__global__ __launch_bounds__(256) void a3v_kernel(const float* __restrict__ qkv, const float* __restrict__ ql,
                                                  const float* __restrict__ kT, float* __restrict__ av){
  __shared__ float qs[64];
  __shared__ float sc[NPAD];
  __shared__ float red[256];
  int blk = blockIdx.x; int bh = blk >> 8, m = blk & 255;
  int b = bh >> 3, hh = bh & 7;
  int t = threadIdx.x;
  if (t < 64) qs[t] = ql[((size_t)bh * 256 + m) * 64 + t];
  __syncthreads();
  const float* kb = kT + (size_t)bh * 64 * NPAD;
  float lmax = -3.4e38f;
  // n in [0,4096): float4 per thread per pass; tail [4096,4352) scalar
  #pragma unroll
  for (int p = 0; p < 4; ++p) {
    int n0 = (t << 2) + (p << 10);
    float4 s4 = make_float4(0.f,0.f,0.f,0.f);
    #pragma unroll
    for (int d = 0; d < 64; ++d) {
      float qd = qs[d];
      float4 kv = *(const float4*)&kb[(size_t)d * NPAD + n0];
      s4.x += qd*kv.x; s4.y += qd*kv.y; s4.z += qd*kv.z; s4.w += qd*kv.w;
    }
    *(float4*)&sc[n0] = s4;
    lmax = fmaxf(lmax, fmaxf(fmaxf(s4.x, s4.y), fmaxf(s4.z, s4.w)));
  }
  { int n = 4096 + t;
    float s = 0.f;
    #pragma unroll
    for (int d = 0; d < 64; ++d) s += qs[d] * kb[(size_t)d * NPAD + n];
    sc[n] = s; lmax = fmaxf(lmax, s); }
  float mx = blk_max(lmax, red);
  float lsum = 0.f;
  for (int n = t; n < NPAD; n += 256) { float e = expf(sc[n] - mx); sc[n] = e; lsum += e; }
  float denom = blk_sum(lsum, red);
  int d = t & 63, ch = t >> 6;
  float p0 = 0.f, p1 = 0.f;
  const float* vbase = qkv + (size_t)b * NPAD * NT + 1024 + hh * 64 + d;
  for (int n = ch; n < NPAD; n += 8) {
    p0 += sc[n]     * vbase[(size_t)n * NT];
    p1 += sc[n + 4] * vbase[(size_t)(n + 4) * NT];
  }
  red[t] = p0 + p1; __syncthreads();
  if (ch == 0) {
    float tot = red[d] + red[64 + d] + red[128 + d] + red[192 + d];
    av[((size_t)bh * 256 + m) * 64 + d] = tot / denom;
  }
}

// ---------------- depthwise 33x1 residual conv on v -> merged ----------------
__global__ __launch_bounds__(256) void conv_res(const float* __restrict__ qkv, const float* __restrict__ rk,
                                                float* __restrict__ merged){
  __shared__ float rks[264];
  int t = threadIdx.x;
  for (int i = t; i < 264; i += 256) rks[i] = rk[i];
  __syncthreads();
  size_t idx = (size_t)blockIdx.x * 256 + t;
  int c = (int)(idx & 511);
  int n = (int)((idx >> 9) % NPAD);
  int b = (int)(idx / ((size_t)512 * NPAD));
  int hh = c >> 6;
  float acc = 0.f;
  #pragma unroll
  for (int kk = 0; kk < 33; ++kk) {
    int nn = n + kk - 16;
    if (nn >= 0 && nn < NPAD)
      acc += rks[hh * 33 + kk] * qkv[((size_t)b * NPAD + nn) * NT + 1024 + c];
  }
  merged[((size_t)b * NPAD + n) * DIM + c] = acc;
}

// ---------------- merged += softmax(q @ kl^T) @ zav (fp32, coalesced via klT) ----------------
__global__ __launch_bounds__(256) void a1_out(const float* __restrict__ qkv, const float* __restrict__ klT,
                                              const float* __restrict__ zav, float* __restrict__ merged){
  __shared__ float qs[64]; __shared__ float sc[256]; __shared__ float red[256];
  int blk = blockIdx.x;            // bh*NPAD + n
  int n = blk % NPAD; int bh = blk / NPAD; int b = bh >> 3, hh = bh & 7;
  int t = threadIdx.x;
  if (t < 64) qs[t] = 0.125f * qkv[((size_t)b * NPAD + n) * NT + hh * 64 + t];
  __syncthreads();
  const float* kb = klT + (size_t)bh * 16384;
  float s = 0.f;
  #pragma unroll
  for (int d = 0; d < 64; ++d) s += qs[d] * kb[d * 256 + t];
  float mx = blk_max(s, red);
  float e = expf(s - mx);
  float denom = blk_sum(e, red);
  sc[t] = e; __syncthreads();
  int d = t & 63, ch = t >> 6;
  float p = 0.f;
  #pragma unroll 4
  for (int m = ch; m < 256; m += 4) p += sc[m] * zav[((size_t)bh * 256 + m) * 64 + d];
  red[t] = p; __syncthreads();
  if (ch == 0) {
    float tot = red[d] + red[64 + d] + red[128 + d] + red[192 + d];
    merged[((size_t)b * NPAD + n) * DIM + hh * 64 + d] += tot / denom;
  }
}

// ---------------- PPEG depthwise convs ----------------
__global__ __launch_bounds__(256) void dwconv(const float* __restrict__ hsrc,
    const float* __restrict__ w7, const float* __restrict__ b7,
    const float* __restrict__ w5, const float* __restrict__ b5,
    const float* __restrict__ w3, const float* __restrict__ b3,
    float* __restrict__ hdst){
  size_t idx = (size_t)blockIdx.x * 256 + threadIdx.x;
  int c = (int)(idx & 511);
  int sp = (int)((idx >> 9) & 4095);
  int b = (int)(idx >> 21);
  int y = sp >> 6, x = sp & 63;
  const float* fb = hsrc + ((size_t)b * N1 + 1) * DIM + c;
  float acc = fb[(size_t)sp * DIM] + b7[c] + b5[c] + b3[c];
  for (int ky = 0; ky < 7; ++ky) { int yy = y + ky - 3; if (yy < 0 || yy >= 64) continue;
    for (int kx = 0; kx < 7; ++kx) { int xx = x + kx - 3; if (xx < 0 || xx >= 64) continue;
      acc += w7[(size_t)c * 49 + ky * 7 + kx] * fb[(size_t)(yy * 64 + xx) * DIM]; } }
  for (int ky = 0; ky < 5; ++ky) { int yy = y + ky - 2; if (yy < 0 || yy >= 64) continue;
    for (int kx = 0; kx < 5; ++kx) { int xx = x + kx - 2; if (xx < 0 || xx >= 64) continue;
      acc += w5[(size_t)c * 25 + ky * 5 + kx] * fb[(size_t)(yy * 64 + xx) * DIM]; } }
  for (int ky = 0; ky < 3; ++ky) { int yy = y + ky - 1; if (yy < 0 || yy >= 64) continue;
    for (int kx = 0; kx < 3; ++kx) { int xx = x + kx - 1; if (xx < 0 || xx >= 64) continue;
      acc += w3[(size_t)c * 9 + ky * 3 + kx] * fb[(size_t)(yy * 64 + xx) * DIM]; } }
  hdst[((size_t)b * N1 + 1 + sp) * DIM + c] = acc;
}

__global__ void set_cls(float* h, const float* cls){
  int t = threadIdx.x;
  if (t < 1024) { int b = t >> 9, c = t & 511; h[(size_t)b * N1 * DIM + c] = cls[c]; }
}
__global__ void copy_cls(float* dst, const float* src){
  int t = threadIdx.x;
  if (t < 1024) { int b = t >> 9, c = t & 511; dst[(size_t)b * N1 * DIM + c] = src[(size_t)b * N1 * DIM + c]; }
}

__global__ __launch_bounds__(256) void final_ln(const float* __restrict__ h2, const float* __restrict__ g,
                                                const float* __restrict__ bt, float* __restrict__ hcls){
  __shared__ double red[256];
  int b = blockIdx.x, t = threadIdx.x;
  const float* x = h2 + (size_t)b * N1 * DIM;
  double x0 = (double)x[t], x1 = (double)x[t + 256];
  double mu = blk_sumd(x0 + x1, red) * (1.0/512.0);
  double d0 = x0 - mu, d1 = x1 - mu;
  double var = blk_sumd(d0*d0 + d1*d1, red) * (1.0/512.0);
  double inv = 1.0 / sqrt(var + 1e-5);
  hcls[b * 512 + t]       = (float)(d0 * inv * (double)g[t]       + (double)bt[t]);
  hcls[b * 512 + t + 256] = (float)(d1 * inv * (double)g[t + 256] + (double)bt[t + 256]);
}

__global__ void build_xc(const float* __restrict__ hcls, const float* __restrict__ reh, float* __restrict__ xc){
  size_t idx = (size_t)blockIdx.x * 256 + threadIdx.x;
  int row = (int)(idx >> 9), c = (int)(idx & 511);
  xc[idx] = (row < 2) ? hcls[row * 512 + c] : reh[(size_t)(row - 2) * 512 + c];
}

__global__ __launch_bounds__(256) void norms_k(const float* __restrict__ xg, double* __restrict__ rn){
  __shared__ double red[256];
  int i = blockIdx.x, t = threadIdx.x;
  double a = (double)xg[(size_t)i * 512 + t], b = (double)xg[(size_t)i * 512 + t + 256];
  double s = blk_sumd(a*a + b*b, red);
  if (t == 0) rn[i] = sqrt(s);
}

__global__ __launch_bounds__(256) void topk_k(const float* __restrict__ xg, const double* __restrict__ rn,
                                              int* __restrict__ idxb){
  __shared__ double sc[256]; __shared__ double redv[256]; __shared__ int redi[256];
  int i = blockIdx.x, j = threadIdx.x;
  const float* xi = xg + (size_t)i * 512;
  const float* xj = xg + (size_t)j * 512;
  double s = 0.;
  for (int c = 0; c < 512; ++c) s += (double)xi[c] * (double)xj[c];
  s /= (rn[i] * rn[j]);
  sc[j] = s; __syncthreads();
  for (int r = 0; r < 4; ++r) {
    redv[j] = sc[j]; redi[j] = j; __syncthreads();
    for (int st = 128; st > 0; st >>= 1) {
      if (j < st) {
        if (redv[j + st] > redv[j] || (redv[j + st] == redv[j] && redi[j + st] < redi[j])) {
          redv[j] = redv[j + st]; redi[j] = redi[j + st];
        }
      }
      __syncthreads();
    }
    if (j == 0) { idxb[i * 4 + r] = redi[0]; sc[redi[0]] = -1e300; }
    __syncthreads();
  }
}

__global__ void edge_k(const float* __restrict__ xg, const int* __restrict__ idxb, float* __restrict__ edge){
  size_t idx = (size_t)blockIdx.x * 256 + threadIdx.x;
  int i = (int)(idx >> 9), c = (int)(idx & 511);
  const int* id = idxb + i * 4;
  edge[idx] = 0.25f * (xg[(size_t)id[0]*512 + c] + xg[(size_t)id[1]*512 + c] +
                       xg[(size_t)id[2]*512 + c] + xg[(size_t)id[3]*512 + c]);
}
__global__ void h1gather_k(const float* __restrict__ h1, const int* __restrict__ idxb, float* __restrict__ out){
  size_t idx = (size_t)blockIdx.x * 256 + threadIdx.x;
  int i = (int)(idx >> 9), c = (int)(idx & 511);
  const int* id = idxb + i * 4;
  out[idx] = h1[idx] + 0.25f * (h1[(size_t)id[0]*512 + c] + h1[(size_t)id[1]*512 + c] +
                                h1[(size_t)id[2]*512 + c] + h1[(size_t)id[3]*512 + c]);
}
__global__ void vadd_k(const float* __restrict__ a, const float* __restrict__ b, float* __restrict__ c){
  size_t idx = (size_t)blockIdx.x * 256 + threadIdx.x;
  c[idx] = a[idx] + b[idx];
}

__global__ void logits2(const float* __restrict__ src, const float* __restrict__ w,
                        const float* __restrict__ bias, float* __restrict__ out){
  int rc = blockIdx.x; int r = rc >> 1, c = rc & 1;
  int t = threadIdx.x; // 64
  double s = 0.;
  for (int k = t; k < 512; k += 64) s += (double)src[(size_t)r * 512 + k] * (double)w[(size_t)c * 512 + k];
  for (int off = 32; off > 0; off >>= 1) s += __shfl_down(s, off);
  if (t == 0) out[rc] = (float)(s + (double)bias[c]);
}

__global__ void sentinel_k(float* out){ if (threadIdx.x < 12) out[threadIdx.x] = 1e30f; }

// ---------------- host-side nystrom block ----------------
struct NysBufs {
  float *pad, *qkv, *ql, *kl, *klT, *av, *zav, *merged;
  float *a2, *zA, *zB, *az, *t1, *t2, *kT, *scal;
};

static void run_nystrom(hipStream_t stream, float* hbuf,
                        const float* lng, const float* lnb, const float* qkvw,
                        const float* outw, const float* outb, const float* rk,
                        const NysBufs& w)
{
  ln_pad<<<BB * NPAD, 256, 0, stream>>>(hbuf, w.pad, lng, lnb);
  gemm_f32<<<dim3(NT/64, (BB*NPAD)/64), 256, 0, stream>>>(w.pad, qkvw, nullptr, nullptr, w.qkv,
                                                          BB*NPAD, NT, DIM, 0);
  // pad is dead; a2/zA/zB/az overlay it.
  landmark<<<BB * NH * LM, 64, 0, stream>>>(w.qkv, w.ql, w.kl);
  transpose_kl<<<dim3(LM/64, 16), 256, 0, stream>>>(w.kl, w.klT);
  a2_kernel<<<BB * NH * LM, 256, 0, stream>>>(w.ql, w.klT, w.a2);
  colrow_max<<<16, 256, 0, stream>>>(w.a2, w.scal);
  scal_red<<<1, 64, 0, stream>>>(w.scal);
  z0_kernel<<<4096, 256, 0, stream>>>(w.a2, w.zA, w.scal);
  // kT overlays merged; must be consumed (a3v) before pinv's t1/t2 reuse merged.
  transpose_k<<<dim3(NPAD/64, 16), 256, 0, stream>>>(w.qkv, w.kT);
  a3v_kernel<<<BB * NH * LM, 256, 0, stream>>>(w.qkv, w.ql, w.kT, w.av);
  float* zc = w.zA; float* zn = w.zB;
  for (int it = 0; it < 6; ++it) {
    mm_bf<<<dim3(4,8,16), 256, 0, stream>>>(w.a2, zc, w.az, w.t1, 256, 1.f, 0.f, 7.f);
    mm_bf<<<dim3(4,8,16), 256, 0, stream>>>(w.az, w.t1, w.t2, nullptr, 256, -1.f, 15.f, 0.f);
    mm_bf<<<dim3(4,8,16), 256, 0, stream>>>(w.az, w.t2, w.t1, nullptr, 256, -1.f, 13.f, 0.f);
    mm_bf<<<dim3(4,8,16), 256, 0, stream>>>(zc, w.t1, zn, nullptr, 256, 0.25f, 0.f, 0.f);
    float* tmp = zc; zc = zn; zn = tmp;
  }
  mm_bf<<<dim3(1,8,16), 256, 0, stream>>>(zc, w.av, w.zav, nullptr, 64, 1.f, 0.f, 0.f);
  // t1/t2 dead; conv_res reinitializes the merged region.
  conv_res<<<(BB * NPAD * DIM) / 256, 256, 0, stream>>>(w.qkv, rk, w.merged);
  a1_out<<<BB * NH * NPAD, 256, 0, stream>>>(w.qkv, w.klT, w.zav, w.merged);
  for (int b = 0; b < BB; ++b)
    gemm_f32<<<dim3(DIM/64, (N1+63)/64), 256, 0, stream>>>(w.merged + ((size_t)b*NPAD + PADR)*DIM,
                                                           outw, outb,
                                                           hbuf + (size_t)b*N1*DIM,
                                                           hbuf + (size_t)b*N1*DIM,
                                                           N1, DIM, DIM, 0);
}

extern "C" void kernel_launch(void* const* d_in, const int* in_sizes, int n_in,
                              void* d_out, int out_size, void* d_ws, size_t ws_size,
                              hipStream_t stream) {
  (void)in_sizes; (void)n_in; (void)out_size;
  const float* x        = (const float*)d_in[0];
  const float* fc1_w    = (const float*)d_in[1];
  const float* fc1_b    = (const float*)d_in[2];
  const float* cls_tok  = (const float*)d_in[3];
  const float* ln1_g    = (const float*)d_in[4];
  const float* ln1_b    = (const float*)d_in[5];
  const float* qkv1_w   = (const float*)d_in[6];
  const float* out1_w   = (const float*)d_in[7];
  const float* out1_b   = (const float*)d_in[8];
  const float* res1_k   = (const float*)d_in[9];
  const float* ppeg_w7  = (const float*)d_in[10];
  const float* ppeg_b7  = (const float*)d_in[11];
  const float* ppeg_w5  = (const float*)d_in[12];
  const float* ppeg_b5  = (const float*)d_in[13];
  const float* ppeg_w3  = (const float*)d_in[14];
  const float* ppeg_b3  = (const float*)d_in[15];
  const float* ln2_g    = (const float*)d_in[16];
  const float* ln2_b    = (const float*)d_in[17];
  const float* qkv2_w   = (const float*)d_in[18];
  const float* out2_w   = (const float*)d_in[19];
  const float* out2_b   = (const float*)d_in[20];
  const float* res2_k   = (const float*)d_in[21];
  const float* norm_g   = (const float*)d_in[22];
  const float* norm_b   = (const float*)d_in[23];
  const float* fc2_w    = (const float*)d_in[24];
  const float* fc2_b    = (const float*)d_in[25];
  const float* dsl_w1   = (const float*)d_in[26];
  const float* dsl_b1   = (const float*)d_in[27];
  const float* dsl_w2   = (const float*)d_in[28];
  const float* dsl_b2   = (const float*)d_in[29];
  const float* gcn_w1   = (const float*)d_in[30];
  const float* gcn_we   = (const float*)d_in[31];
  const float* gcn_b1   = (const float*)d_in[32];
  const float* gcn_w2   = (const float*)d_in[33];
  const float* gcn_b2   = (const float*)d_in[34];
  const float* gcn_hw   = (const float*)d_in[35];
  const float* gcn_hb   = (const float*)d_in[36];
  const float* gcn_dw   = (const float*)d_in[37];
  const float* gcn_db   = (const float*)d_in[38];
  const float* rehearsal= (const float*)d_in[39];
  float* out = (float*)d_out;

  char* base = (char*)d_ws;
  size_t off = 0;
  auto takeb = [&](size_t bytes) { void* p = base + off; off += (bytes + 255) & ~(size_t)255; return p; };

  float* h    = (float*)takeb((size_t)BB * N1 * DIM * 4);
  float* h2   = (float*)takeb((size_t)BB * N1 * DIM * 4);
  NysBufs nb;
  nb.pad    = (float*)takeb((size_t)BB * NPAD * DIM * 4);     // 17.8 MB; a2/zA/zB/az overlay
  nb.qkv    = (float*)takeb((size_t)BB * NPAD * NT * 4);
  nb.ql     = (float*)takeb((size_t)BB * NH * LM * DH * 4);
  nb.kl     = (float*)takeb((size_t)BB * NH * LM * DH * 4);
  nb.klT    = (float*)takeb((size_t)BB * NH * LM * DH * 4);
  nb.av     = (float*)takeb((size_t)BB * NH * LM * DH * 4);
  nb.zav    = (float*)takeb((size_t)BB * NH * LM * DH * 4);
  nb.merged = (float*)takeb((size_t)BB * NPAD * DIM * 4);     // 17.8 MB; kT then t1/t2 overlay
  nb.scal   = (float*)takeb(64 * 4);
  float* hcls = (float*)takeb((size_t)BB * DIM * 4);
  float* xc   = (float*)takeb((size_t)256 * 512 * 4);
  float* xg1  = (float*)takeb((size_t)256 * 256 * 4);
  float* xg   = (float*)takeb((size_t)256 * 512 * 4);
  double* rn  = (double*)takeb(256 * 8);
  int*   idxb = (int*)takeb(1024 * 4);
  float* edge = (float*)takeb((size_t)256 * 512 * 4);
  float* h1g  = (float*)takeb((size_t)256 * 512 * 4);
  float* h1pn = (float*)takeb((size_t)256 * 512 * 4);
  float* h2g  = (float*)takeb((size_t)256 * 512 * 4);

  // overlays (stream-ordered liveness):
  const size_t MAT = (size_t)16 * 65536;      // 1M floats = 4 MB
  nb.a2 = nb.pad;
  nb.zA = nb.pad + MAT;
  nb.zB = nb.pad + 2 * MAT;
  nb.az = nb.pad + 3 * MAT;                    // 16 MB total <= pad's 17.8 MB
  nb.kT = nb.merged;                           // 17.8 MB exact
  nb.t1 = nb.merged;
  nb.t2 = nb.merged + MAT;

  if (ws_size < off) { sentinel_k<<<1, 64, 0, stream>>>(out); return; }

  // --- stage A: fc1 + cls ---
  set_cls<<<1, 1024, 0, stream>>>(h, cls_tok);
  for (int b = 0; b < BB; ++b)
    gemm_f32<<<dim3(DIM/64, NSEQ/64), 256, 0, stream>>>(x + (size_t)b*NSEQ*DIM, fc1_w, fc1_b, nullptr,
                                                        h + ((size_t)b*N1 + 1)*DIM, NSEQ, DIM, DIM, 1);
  // --- nystrom block 1 (residual into h) ---
  run_nystrom(stream, h, ln1_g, ln1_b, qkv1_w, out1_w, out1_b, res1_k, nb);

  // --- PPEG ---
  copy_cls<<<1, 1024, 0, stream>>>(h2, h);
  dwconv<<<(BB * NSEQ * DIM) / 256, 256, 0, stream>>>(h, ppeg_w7, ppeg_b7, ppeg_w5, ppeg_b5,
                                                      ppeg_w3, ppeg_b3, h2);
  // --- nystrom block 2 (residual into h2) ---
  run_nystrom(stream, h2, ln2_g, ln2_b, qkv2_w, out2_w, out2_b, res2_k, nb);

  // --- final LN (row 0) + heads ---
  final_ln<<<BB, 256, 0, stream>>>(h2, norm_g, norm_b, hcls);
  logits2<<<4, 64, 0, stream>>>(hcls, fc2_w, fc2_b, out + 0);

  // --- GCN branch ---
  build_xc<<<512, 256, 0, stream>>>(hcls, rehearsal, xc);
  gemm_f32<<<dim3(256/64, 4), 256, 0, stream>>>(xc, dsl_w1, dsl_b1, nullptr, xg1, 256, 256, 512, 2);
  gemm_f32<<<dim3(512/64, 4), 256, 0, stream>>>(xg1, dsl_w2, dsl_b2, nullptr, xg, 256, 512, 256, 2);
  norms_k<<<256, 256, 0, stream>>>(xg, rn);
  topk_k<<<256, 256, 0, stream>>>(xg, rn, idxb);
  edge_k<<<512, 256, 0, stream>>>(xg, idxb, edge);
  vadd_k<<<512, 256, 0, stream>>>(xg, edge, h1pn);
  gemm_f32<<<dim3(512/64, 4), 256, 0, stream>>>(h1pn, gcn_w1, nullptr, nullptr, h1g, 256, 512, 512, 0);
  gemm_f32<<<dim3(512/64, 4), 256, 0, stream>>>(edge, gcn_we, gcn_b1, h1g, h1g, 256, 512, 512, 1);
  h1gather_k<<<512, 256, 0, stream>>>(h1g, idxb, h1pn);
  gemm_f32<<<dim3(512/64, 4), 256, 0, stream>>>(h1pn, gcn_w2, gcn_b2, nullptr, h2g, 256, 512, 512, 0);
  logits2<<<4, 64, 0, stream>>>(h2g, gcn_hw, gcn_hb, out + 4);
  logits2<<<4, 64, 0, stream>>>(h1g, gcn_dw, gcn_db, out + 8);
}

// Round 5
// 4678.478 us; speedup vs baseline: 2.3189x; 1.6132x over previous
//
#include <hip/hip_runtime.h>
#include <math.h>

#define BB 2
#define NSEQ 4096
#define N1 4097
#define NPAD 4352
#define PADR 255
#define DIM 512
#define NH 8
#define DH 64
#define LM 256
#define NT 1536

// ---------------- block reduce helpers (blockDim.x == 256) ----------------
__device__ __forceinline__ float blk_sum(float v, float* red){
  int t = threadIdx.x;
  red[t] = v; __syncthreads();
  for (int s = 128; s > 0; s >>= 1){ if (t < s) red[t] += red[t+s]; __syncthreads(); }
  float r = red[0]; __syncthreads(); return r;
}
__device__ __forceinline__ float blk_max(float v, float* red){
  int t = threadIdx.x;
  red[t] = v; __syncthreads();
  for (int s = 128; s > 0; s >>= 1){ if (t < s) red[t] = fmaxf(red[t], red[t+s]); __syncthreads(); }
  float r = red[0]; __syncthreads(); return r;
}
__device__ __forceinline__ double blk_sumd(double v, double* red){
  int t = threadIdx.x;
  red[t] = v; __syncthreads();
  for (int s = 128; s > 0; s >>= 1){ if (t < s) red[t] += red[t+s]; __syncthreads(); }
  double r = red[0]; __syncthreads(); return r;
}

// ---------------- fp32 GEMM 128x128 tile, 8x8/thread, transposed LDS ----------------
// C = act(A @ W^T + bias + res);  A: MxK, W: NxK (row-major). K % 32 == 0, N % 128 == 0.
__global__ __launch_bounds__(256) void gemm_f32(
    const float* __restrict__ A, const float* __restrict__ W,
    const float* __restrict__ bias, const float* __restrict__ res,
    float* __restrict__ C, int M, int N, int K, int act)
{
  __shared__ float AsT[32][132], WsT[32][132];
  int t = threadIdx.x;
  int tx = t & 15, ty = t >> 4;
  int row0 = blockIdx.y * 128, col0 = blockIdx.x * 128;
  float acc[8][8] = {};
  for (int k0 = 0; k0 < K; k0 += 32) {
    for (int i = t; i < 1024; i += 256) {
      int r = i >> 3, c4 = (i & 7) << 2;
      int gr = row0 + r;
      float4 va = make_float4(0.f,0.f,0.f,0.f);
      if (gr < M) va = *(const float4*)&A[(size_t)gr * K + k0 + c4];
      AsT[c4][r] = va.x; AsT[c4+1][r] = va.y; AsT[c4+2][r] = va.z; AsT[c4+3][r] = va.w;
      int wr = col0 + r;
      float4 vw = make_float4(0.f,0.f,0.f,0.f);
      if (wr < N) vw = *(const float4*)&W[(size_t)wr * K + k0 + c4];
      WsT[c4][r] = vw.x; WsT[c4+1][r] = vw.y; WsT[c4+2][r] = vw.z; WsT[c4+3][r] = vw.w;
    }
    __syncthreads();
    #pragma unroll
    for (int kk = 0; kk < 32; ++kk) {
      float a[8], w[8];
      *(float4*)&a[0] = *(const float4*)&AsT[kk][ty*8];
      *(float4*)&a[4] = *(const float4*)&AsT[kk][ty*8+4];
      *(float4*)&w[0] = *(const float4*)&WsT[kk][tx*8];
      *(float4*)&w[4] = *(const float4*)&WsT[kk][tx*8+4];
      #pragma unroll
      for (int i = 0; i < 8; ++i)
        #pragma unroll
        for (int j = 0; j < 8; ++j) acc[i][j] += a[i]*w[j];
    }
    __syncthreads();
  }
  for (int i = 0; i < 8; ++i) {
    int r = row0 + ty*8 + i;
    if (r >= M) break;
    for (int j = 0; j < 8; ++j) {
      int c = col0 + tx*8 + j;
      float v = acc[i][j];
      if (bias) v += bias[c];
      if (res)  v += res[(size_t)r * N + c];
      if (act == 1) v = fmaxf(v, 0.f);
      else if (act == 2) v = (v >= 0.f) ? v : 0.01f * v;
      C[(size_t)r * N + c] = v;
    }
  }
}

// ---------------- fp32 batched (16x) GEMM 64x64 tile, 4x4/thread, transposed LDS ----------------
// per bh: A 256x256, B 256xN. C = alpha*(A@B)+diag*I; optional D = diag2*I - C.
__global__ __launch_bounds__(256) void mm_bf(
    const float* __restrict__ A, const float* __restrict__ Bm,
    float* __restrict__ C, float* __restrict__ D,
    int N, float alpha, float diag, float diag2)
{
  int bh = blockIdx.z;
  const float* Ab = A + (size_t)bh * 65536;
  const float* Bb = Bm + (size_t)bh * 256 * N;
  float* Cb = C + (size_t)bh * 256 * N;
  float* Db = D ? (D + (size_t)bh * 256 * N) : (float*)0;
  __shared__ float AsT[32][68], Bs[32][68];
  int t = threadIdx.x;
  int tx = t & 15, ty = t >> 4;
  int row0 = blockIdx.y * 64, col0 = blockIdx.x * 64;
  float acc[4][4] = {};
  for (int k0 = 0; k0 < 256; k0 += 32) {
    for (int i = t; i < 512; i += 256) {
      int r = i >> 3, c4 = (i & 7) << 2;
      float4 va = *(const float4*)&Ab[(size_t)(row0 + r) * 256 + k0 + c4];
      AsT[c4][r] = va.x; AsT[c4+1][r] = va.y; AsT[c4+2][r] = va.z; AsT[c4+3][r] = va.w;
    }
    for (int i = t; i < 512; i += 256) {
      int r = i >> 4, c4 = (i & 15) << 2;
      *(float4*)&Bs[r][c4] = *(const float4*)&Bb[(size_t)(k0 + r) * N + col0 + c4];
    }
    __syncthreads();
    #pragma unroll
    for (int kk = 0; kk < 32; ++kk) {
      float4 a4 = *(const float4*)&AsT[kk][ty*4];
      float4 b4 = *(const float4*)&Bs[kk][tx*4];
      float a[4] = {a4.x,a4.y,a4.z,a4.w}, b[4] = {b4.x,b4.y,b4.z,b4.w};
      #pragma unroll
      for (int i = 0; i < 4; ++i)
        #pragma unroll
        for (int j = 0; j < 4; ++j) acc[i][j] += a[i]*b[j];
    }
    __syncthreads();
  }
  #pragma unroll
  for (int i = 0; i < 4; ++i)
    #pragma unroll
    for (int j = 0; j < 4; ++j) {
      int r = row0 + ty*4 + i, c = col0 + tx*4 + j;
      float v = alpha * acc[i][j];
      if (r == c) v += diag;
      Cb[(size_t)r * N + c] = v;
      if (Db) Db[(size_t)r * N + c] = ((r == c) ? diag2 : 0.f) - v;
    }
}

// ---------------- LN + front zero-pad into (B,NPAD,DIM) ----------------
__global__ __launch_bounds__(256) void ln_pad(const float* __restrict__ hsrc, float* __restrict__ dst,
                                              const float* __restrict__ g, const float* __restrict__ bt){
  __shared__ double red[256];
  int row = blockIdx.x;
  int b = row / NPAD, r = row % NPAD;
  float* drow = dst + (size_t)row * DIM;
  int t = threadIdx.x;
  if (r < PADR) { drow[t] = 0.f; drow[t + 256] = 0.f; return; }
  const float* x = hsrc + ((size_t)b * N1 + (r - PADR)) * DIM;
  double x0 = (double)x[t], x1 = (double)x[t + 256];
  double mu = blk_sumd(x0 + x1, red) * (1.0/512.0);
  double d0 = x0 - mu, d1 = x1 - mu;
  double var = blk_sumd(d0*d0 + d1*d1, red) * (1.0/512.0);
  double inv = 1.0 / sqrt(var + 1e-5);
  drow[t]       = (float)(d0 * inv * (double)g[t]       + (double)bt[t]);
  drow[t + 256] = (float)(d1 * inv * (double)g[t + 256] + (double)bt[t + 256]);
}

// ---------------- landmarks: ql (scaled by 1/8), kl ----------------
__global__ void landmark(const float* __restrict__ qkv, float* __restrict__ ql, float* __restrict__ kl){
  int blk = blockIdx.x;            // bh*256 + m
  int bh = blk >> 8, m = blk & 255;
  int b = bh >> 3, hh = bh & 7;
  int d = threadIdx.x;             // 64
  float sq = 0.f, sk = 0.f;
  for (int l = 0; l < 17; ++l) {
    size_t o = ((size_t)b * NPAD + m * 17 + l) * NT + hh * 64 + d;
    sq += qkv[o];
    sk += qkv[o + 512];
  }
  ql[((size_t)bh * 256 + m) * 64 + d] = 0.125f * sq / 17.f;
  kl[((size_t)bh * 256 + m) * 64 + d] = sk / 17.f;
}

// klT[bh][d][m] = kl[bh][m][d]; grid (LM/64, 16)
__global__ __launch_bounds__(256) void transpose_kl(const float* __restrict__ kl, float* __restrict__ klT){
  __shared__ float tile[64][65];
  int bh = blockIdx.y;
  int m0 = blockIdx.x * 64;
  int t = threadIdx.x;
  for (int i = t; i < 4096; i += 256) {
    int r = i >> 6, c = i & 63;
    tile[r][c] = kl[((size_t)bh * 256 + m0 + r) * 64 + c];
  }
  __syncthreads();
  float* kb = klT + (size_t)bh * 64 * 256;
  for (int i = t; i < 4096; i += 256) {
    int d = i >> 6, mm = i & 63;
    kb[(size_t)d * 256 + m0 + mm] = tile[mm][d];
  }
}

// ---------------- a2 = softmax(ql @ kl^T) ----------------
__global__ __launch_bounds__(256) void a2_kernel(const float* __restrict__ ql, const float* __restrict__ klT,
                                                 float* __restrict__ a2){
  __shared__ float qs[64]; __shared__ float red[256];
  int blk = blockIdx.x;            // bh*256 + i
  int bh = blk >> 8, i = blk & 255;
  int t = threadIdx.x;
  if (t < 64) qs[t] = ql[((size_t)bh * 256 + i) * 64 + t];
  __syncthreads();
  const float* kb = klT + (size_t)bh * 16384;
  float s = 0.f;
  #pragma unroll
  for (int d = 0; d < 64; ++d) s += qs[d] * kb[d * 256 + t];
  float mx = blk_max(s, red);
  float e = expf(s - mx);
  float sum = blk_sum(e, red);
  a2[((size_t)bh * 256 + i) * 256 + t] = e / sum;
}

// per-(b,h) max colsum / rowsum
__global__ __launch_bounds__(256) void colrow_max(const float* __restrict__ a2, float* __restrict__ scal){
  __shared__ float red[256];
  int bh = blockIdx.x, t = threadIdx.x;
  const float* A = a2 + (size_t)bh * 65536;
  float cs = 0.f, rs = 0.f;
  for (int i = 0; i < 256; ++i) cs += A[(size_t)i * 256 + t];
  for (int j = 0; j < 256; ++j) rs += A[(size_t)t * 256 + j];
  float cmax = blk_max(cs, red);
  float rmax = blk_max(rs, red);
  if (t == 0) { scal[bh] = cmax; scal[16 + bh] = rmax; }
}
__global__ void scal_red(float* scal){
  if (threadIdx.x == 0) {
    float cm = scal[0], rm = scal[16];
    for (int i = 1; i < 16; ++i) { cm = fmaxf(cm, scal[i]); rm = fmaxf(rm, scal[16 + i]); }
    scal[32] = 1.f / (rm * cm);
  }
}
// z0 = a2^T * invscale
__global__ void z0_kernel(const float* __restrict__ a2, float* __restrict__ z, const float* __restrict__ scal){
  size_t idx = (size_t)blockIdx.x * 256 + threadIdx.x;
  size_t bh = idx >> 16;
  int rc = (int)(idx & 65535);
  int r = rc >> 8, c = rc & 255;
  z[idx] = a2[(bh << 16) + (size_t)c * 256 + r] * scal[32];
}

// ================= flash-attention tiles (fp32, 64x64x64, online softmax) =================
// fa3v: Q=ql (256 rows/bh), K=qkv+512, V=qkv+1024 (NPAD rows); 4-way split over n; partial out.
// grid (4 parts, 4 qtiles, 16 bh)
__global__ __launch_bounds__(256) void fa3v_kernel(const float* __restrict__ qkv, const float* __restrict__ ql,
                                                   float* __restrict__ accp, float* __restrict__ mlp){
  int part = blockIdx.x, qt = blockIdx.y, bh = blockIdx.z;
  int b = bh >> 3, hh = bh & 7;
  int t = threadIdx.x, tx = t & 15, ty = t >> 4;
  __shared__ float QsT[64][68];
  __shared__ float KV[64][68];
  __shared__ float Ss[64][68];
  __shared__ float redm[64][4];
  __shared__ float mrow[64], lrow[64], scales[64];
  for (int i = t; i < 4096; i += 256) {
    int r = i >> 6, c = i & 63;
    QsT[c][r] = ql[((size_t)bh * 256 + qt * 64 + r) * 64 + c];
  }
  if (t < 64) { mrow[t] = -3.4e38f; lrow[t] = 0.f; }
  float acc[4][4] = {};
  __syncthreads();
  int rr = t >> 2, sg = (t & 3) << 4;
  for (int tile = 0; tile < 17; ++tile) {
    int nbase = part * 1088 + tile * 64;
    for (int i = t; i < 4096; i += 256) {
      int r = i >> 6, c = i & 63;
      KV[c][r] = qkv[((size_t)b * NPAD + nbase + r) * NT + 512 + hh * 64 + c];
    }
    __syncthreads();
    float sreg[4][4] = {};
    #pragma unroll 16
    for (int d = 0; d < 64; ++d) {
      float4 a4 = *(const float4*)&QsT[d][ty*4];
      float4 k4 = *(const float4*)&KV[d][tx*4];
      float a[4] = {a4.x,a4.y,a4.z,a4.w}, k[4] = {k4.x,k4.y,k4.z,k4.w};
      #pragma unroll
      for (int i = 0; i < 4; ++i)
        #pragma unroll
        for (int j = 0; j < 4; ++j) sreg[i][j] += a[i]*k[j];
    }
    __syncthreads();   // done reading K
    #pragma unroll
    for (int i = 0; i < 4; ++i)
      *(float4*)&Ss[ty*4+i][tx*4] = make_float4(sreg[i][0], sreg[i][1], sreg[i][2], sreg[i][3]);
    for (int i = t; i < 4096; i += 256) {       // V in row layout, reusing KV
      int r = i >> 6, c = i & 63;
      KV[r][c] = qkv[((size_t)b * NPAD + nbase + r) * NT + 1024 + hh * 64 + c];
    }
    __syncthreads();   // Ss + V ready
    float lm = -3.4e38f;
    #pragma unroll
    for (int c = 0; c < 16; ++c) lm = fmaxf(lm, Ss[rr][sg + c]);
    redm[rr][t & 3] = lm;
    float mold = mrow[rr];
    float rm = fmaxf(fmaxf(redm[rr][0], redm[rr][1]), fmaxf(redm[rr][2], redm[rr][3]));
    float mnew = fmaxf(mold, rm);
    float sc_r = expf(mold - mnew);
    if ((t & 3) == 0) { scales[rr] = sc_r; mrow[rr] = mnew; }
    float ls = 0.f;
    #pragma unroll
    for (int c = 0; c < 16; ++c) { float p = expf(Ss[rr][sg+c] - mnew); Ss[rr][sg+c] = p; ls += p; }
    redm[rr][t & 3] = ls;
    __syncthreads();   // exp'd Ss + scales + redm visible to all
    if ((t & 3) == 0) lrow[rr] = lrow[rr] * sc_r + redm[rr][0]+redm[rr][1]+redm[rr][2]+redm[rr][3];
    #pragma unroll
    for (int i = 0; i < 4; ++i) {
      float s = scales[ty*4+i];
      acc[i][0]*=s; acc[i][1]*=s; acc[i][2]*=s; acc[i][3]*=s;
    }
    #pragma unroll 8
    for (int m = 0; m < 64; ++m) {
      float4 v4 = *(const float4*)&KV[m][tx*4];
      float p0 = Ss[ty*4][m], p1 = Ss[ty*4+1][m], p2 = Ss[ty*4+2][m], p3 = Ss[ty*4+3][m];
      acc[0][0]+=p0*v4.x; acc[0][1]+=p0*v4.y; acc[0][2]+=p0*v4.z; acc[0][3]+=p0*v4.w;
      acc[1][0]+=p1*v4.x; acc[1][1]+=p1*v4.y; acc[1][2]+=p1*v4.z; acc[1][3]+=p1*v4.w;
      acc[2][0]+=p2*v4.x; acc[2][1]+=p2*v4.y; acc[2][2]+=p2*v4.z; acc[2][3]+=p2*v4.w;
      acc[3][0]+=p3*v4.x; acc[3][1]+=p3*v4.y; acc[3][2]+=p3*v4.z; acc[3][3]+=p3*v4.w;
    }
    __syncthreads();   // before next tile overwrites KV / Ss / lrow updates
  }
  int blk = (bh * 4 + qt) * 4 + part;
  float* ap = accp + (size_t)blk * 4096;
  #pragma unroll
  for (int i = 0; i < 4; ++i)
    *(float4*)&ap[(ty*4+i)*64 + tx*4] = make_float4(acc[i][0], acc[i][1], acc[i][2], acc[i][3]);
  if (t < 64) { mlp[(size_t)blk*128 + t] = mrow[t]; mlp[(size_t)blk*128 + 64 + t] = lrow[t]; }
}

// combine 4 partials -> av ; grid 64 = bh*4+qt
__global__ __launch_bounds__(256) void fa3v_combine(const float* __restrict__ accp, const float* __restrict__ mlp,
                                                    float* __restrict__ av){
  int g = blockIdx.x;
  int t = threadIdx.x;
  int r = t >> 2, sg = (t & 3) << 4;
  int bh = g >> 2, qt = g & 3;
  float mp[4], lp[4];
  #pragma unroll
  for (int p = 0; p < 4; ++p) { mp[p] = mlp[(size_t)(g*4+p)*128 + r]; lp[p] = mlp[(size_t)(g*4+p)*128 + 64 + r]; }
  float M = fmaxf(fmaxf(mp[0],mp[1]), fmaxf(mp[2],mp[3]));
  float w[4]; float L = 0.f;
  #pragma unroll
  for (int p = 0; p < 4; ++p) { w[p] = expf(mp[p] - M); L += w[p] * lp[p]; }
  float invL = 1.f / L;
  #pragma unroll
  for (int c = 0; c < 16; ++c) {
    float s = 0.f;
    #pragma unroll
    for (int p = 0; p < 4; ++p) s += w[p] * accp[(size_t)(g*4+p)*4096 + r*64 + sg + c];
    av[((size_t)(bh*256 + qt*64 + r))*64 + sg + c] = s * invL;
  }
}

// fa1: Q = qkv.q * 0.125 (NPAD rows), K = kl, V = zav (256 rows); merged += P@V.
// grid (68 ntiles, 16 bh)
__global__ __launch_bounds__(256) void fa1_kernel(const float* __restrict__ qkv, const float* __restrict__ kl,
                                                  const float* __restrict__ zav, float* __restrict__ merged){
  int nt = blockIdx.x, bh = blockIdx.y;
  int b = bh >> 3, hh = bh & 7;
  int t = threadIdx.x, tx = t & 15, ty = t >> 4;
  __shared__ float QsT[64][68];
  __shared__ float KV[64][68];
  __shared__ float Ss[64][68];
  __shared__ float redm[64][4];
  __shared__ float mrow[64], lrow[64], scales[64];
  int n0 = nt * 64;
  for (int i = t; i < 4096; i += 256) {
    int r = i >> 6, c = i & 63;
    QsT[c][r] = 0.125f * qkv[((size_t)b * NPAD + n0 + r) * NT + hh * 64 + c];
  }
  if (t < 64) { mrow[t] = -3.4e38f; lrow[t] = 0.f; }
  float acc[4][4] = {};
  __syncthreads();
  int rr = t >> 2, sg = (t & 3) << 4;
  for (int tile = 0; tile < 4; ++tile) {
    int mbase = tile * 64;
    for (int i = t; i < 4096; i += 256) {
      int r = i >> 6, c = i & 63;
      KV[c][r] = kl[((size_t)bh * 256 + mbase + r) * 64 + c];
    }
    __syncthreads();
    float sreg[4][4] = {};
    #pragma unroll 16
    for (int d = 0; d < 64; ++d) {
      float4 a4 = *(const float4*)&QsT[d][ty*4];
      float4 k4 = *(const float4*)&KV[d][tx*4];
      float a[4] = {a4.x,a4.y,a4.z,a4.w}, k[4] = {k4.x,k4.y,k4.z,k4.w};
      #pragma unroll
      for (int i = 0; i < 4; ++i)
        #pragma unroll
        for (int j = 0; j < 4; ++j) sreg[i][j] += a[i]*k[j];
    }
    __syncthreads();
    #pragma unroll
    for (int i = 0; i < 4; ++i)
      *(float4*)&Ss[ty*4+i][tx*4] = make_float4(sreg[i][0], sreg[i][1], sreg[i][2], sreg[i][3]);
    for (int i = t; i < 4096; i += 256) {
      int r = i >> 6, c = i & 63;
      KV[r][c] = zav[((size_t)bh * 256 + mbase + r) * 64 + c];
    }
    __syncthreads();
    float lm = -3.4e38f;
    #pragma unroll
    for (int c = 0; c < 16; ++c) lm = fmaxf(lm, Ss[rr][sg + c]);
    redm[rr][t & 3] = lm;
    float mold = mrow[rr];
    float rm = fmaxf(fmaxf(redm[rr][0], redm[rr][1]), fmaxf(redm[rr][2], redm[rr][3]));
    float mnew = fmaxf(mold, rm);
    float sc_r = expf(mold - mnew);
    if ((t & 3) == 0) { scales[rr] = sc_r; mrow[rr] = mnew; }
    float ls = 0.f;
    #pragma unroll
    for (int c = 0; c < 16; ++c) { float p = expf(Ss[rr][sg+c] - mnew); Ss[rr][sg+c] = p; ls += p; }
    redm[rr][t & 3] = ls;
    __syncthreads();
    if ((t & 3) == 0) lrow[rr] = lrow[rr] * sc_r + redm[rr][0]+redm[rr][1]+redm[rr][2]+redm[rr][3];
    #pragma unroll
    for (int i = 0; i < 4; ++i) {
      float s = scales[ty*4+i];
      acc[i][0]*=s; acc[i][1]*=s; acc[i][2]*=s; acc[i][3]*=s;
    }
    #pragma unroll 8
    for (int m = 0; m < 64; ++m) {
      float4 v4 = *(const float4*)&KV[m][tx*4];
      float p0 = Ss[ty*4][m], p1 = Ss[ty*4+1][m], p2 = Ss[ty*4+2][m], p3 = Ss[ty*4+3][m];
      acc[0][0]+=p0*v4.x; acc[0][1]+=p0*v4.y; acc[0][2]+=p0*v4.z; acc[0][3]+=p0*v4.w;
      acc[1][0]+=p1*v4.x; acc[1][1]+=p1*v4.y; acc[1][2]+=p1*v4.z; acc[1][3]+=p1*v4.w;
      acc[2][0]+=p2*v4.x; acc[2][1]+=p2*v4.y; acc[2][2]+=p2*v4.z; acc[2][3]+=p2*v4.w;
      acc[3][0]+=p3*v4.x; acc[3][1]+=p3*v4.y; acc[3][2]+=p3*v4.z; acc[3][3]+=p3*v4.w;
    }
    __syncthreads();
  }
  #pragma unroll
  for (int i = 0; i < 4; ++i) {
    float invl = 1.f / lrow[ty*4+i];
    float* mp = &merged[((size_t)b * NPAD + n0 + ty*4 + i) * DIM + hh * 64 + tx*4];
    mp[0] += acc[i][0]*invl; mp[1] += acc[i][1]*invl; mp[2] += acc[i][2]*invl; mp[3] += acc[i][3]*invl;
  }
}

// ---------------- depthwise 33x1 residual conv on v -> merged ----------------
__global__ __launch_bounds__(256) void conv_res(const float* __restrict__ qkv, const float* __restrict__ rk,
                                                float* __restrict__ merged){
  __shared__ float rks[264];
  int t = threadIdx.x;
  for (int i = t; i < 264; i += 256) rks[i] = rk[i];
  __syncthreads();
  size_t idx = (size_t)blockIdx.x * 256 + t;
  int c = (int)(idx & 511);
  int n = (int)((idx >> 9) % NPAD);
  int b = (int)(idx / ((size_t)512 * NPAD));
  int hh = c >> 6;
  float acc = 0.f;
  #pragma unroll
  for (int kk = 0; kk < 33; ++kk) {
    int nn = n + kk - 16;
    if (nn >= 0 && nn < NPAD)
      acc += rks[hh * 33 + kk] * qkv[((size_t)b * NPAD + nn) * NT + 1024 + c];
  }
  merged[((size_t)b * NPAD + n) * DIM + c] = acc;
}

// ---------------- PPEG depthwise convs ----------------
__global__ __launch_bounds__(256) void dwconv(const float* __restrict__ hsrc,
    const float* __restrict__ w7, const float* __restrict__ b7,
    const float* __restrict__ w5, const float* __restrict__ b5,
    const float* __restrict__ w3, const float* __restrict__ b3,
    float* __restrict__ hdst){
  size_t idx = (size_t)blockIdx.x * 256 + threadIdx.x;
  int c = (int)(idx & 511);
  int sp = (int)((idx >> 9) & 4095);
  int b = (int)(idx >> 21);
  int y = sp >> 6, x = sp & 63;
  const float* fb = hsrc + ((size_t)b * N1 + 1) * DIM + c;
  float acc = fb[(size_t)sp * DIM] + b7[c] + b5[c] + b3[c];
  for (int ky = 0; ky < 7; ++ky) { int yy = y + ky - 3; if (yy < 0 || yy >= 64) continue;
    for (int kx = 0; kx < 7; ++kx) { int xx = x + kx - 3; if (xx < 0 || xx >= 64) continue;
      acc += w7[(size_t)c * 49 + ky * 7 + kx] * fb[(size_t)(yy * 64 + xx) * DIM]; } }
  for (int ky = 0; ky < 5; ++ky) { int yy = y + ky - 2; if (yy < 0 || yy >= 64) continue;
    for (int kx = 0; kx < 5; ++kx) { int xx = x + kx - 2; if (xx < 0 || xx >= 64) continue;
      acc += w5[(size_t)c * 25 + ky * 5 + kx] * fb[(size_t)(yy * 64 + xx) * DIM]; } }
  for (int ky = 0; ky < 3; ++ky) { int yy = y + ky - 1; if (yy < 0 || yy >= 64) continue;
    for (int kx = 0; kx < 3; ++kx) { int xx = x + kx - 1; if (xx < 0 || xx >= 64) continue;
      acc += w3[(size_t)c * 9 + ky * 3 + kx] * fb[(size_t)(yy * 64 + xx) * DIM]; } }
  hdst[((size_t)b * N1 + 1 + sp) * DIM + c] = acc;
}

__global__ void set_cls(float* h, const float* cls){
  int t = threadIdx.x;
  if (t < 1024) { int b = t >> 9, c = t & 511; h[(size_t)b * N1 * DIM + c] = cls[c]; }
}
__global__ void copy_cls(float* dst, const float* src){
  int t = threadIdx.x;
  if (t < 1024) { int b = t >> 9, c = t & 511; dst[(size_t)b * N1 * DIM + c] = src[(size_t)b * N1 * DIM + c]; }
}

__global__ __launch_bounds__(256) void final_ln(const float* __restrict__ h2, const float* __restrict__ g,
                                                const float* __restrict__ bt, float* __restrict__ hcls){
  __shared__ double red[256];
  int b = blockIdx.x, t = threadIdx.x;
  const float* x = h2 + (size_t)b * N1 * DIM;
  double x0 = (double)x[t], x1 = (double)x[t + 256];
  double mu = blk_sumd(x0 + x1, red) * (1.0/512.0);
  double d0 = x0 - mu, d1 = x1 - mu;
  double var = blk_sumd(d0*d0 + d1*d1, red) * (1.0/512.0);
  double inv = 1.0 / sqrt(var + 1e-5);
  hcls[b * 512 + t]       = (float)(d0 * inv * (double)g[t]       + (double)bt[t]);
  hcls[b * 512 + t + 256] = (float)(d1 * inv * (double)g[t + 256] + (double)bt[t + 256]);
}

__global__ void build_xc(const float* __restrict__ hcls, const float* __restrict__ reh, float* __restrict__ xc){
  size_t idx = (size_t)blockIdx.x * 256 + threadIdx.x;
  int row = (int)(idx >> 9), c = (int)(idx & 511);
  xc[idx] = (row < 2) ? hcls[row * 512 + c] : reh[(size_t)(row - 2) * 512 + c];
}

__global__ __launch_bounds__(256) void norms_k(const float* __restrict__ xg, double* __restrict__ rn){
  __shared__ double red[256];
  int i = blockIdx.x, t = threadIdx.x;
  double a = (double)xg[(size_t)i * 512 + t], b = (double)xg[(size_t)i * 512 + t + 256];
  double s = blk_sumd(a*a + b*b, red);
  if (t == 0) rn[i] = sqrt(s);
}

__global__ __launch_bounds__(256) void topk_k(const float* __restrict__ xg, const double* __restrict__ rn,
                                              int* __restrict__ idxb){
  __shared__ double sc[256]; __shared__ double redv[256]; __shared__ int redi[256];
  int i = blockIdx.x, j = threadIdx.x;
  const float* xi = xg + (size_t)i * 512;
  const float* xj = xg + (size_t)j * 512;
  double s = 0.;
  for (int c = 0; c < 512; ++c) s += (double)xi[c] * (double)xj[c];
  s /= (rn[i] * rn[j]);
  sc[j] = s; __syncthreads();
  for (int r = 0; r < 4; ++r) {
    redv[j] = sc[j]; redi[j] = j; __syncthreads();
    for (int st = 128; st > 0; st >>= 1) {
      if (j < st) {
        if (redv[j + st] > redv[j] || (redv[j + st] == redv[j] && redi[j + st] < redi[j])) {
          redv[j] = redv[j + st]; redi[j] = redi[j + st];
        }
      }
      __syncthreads();
    }
    if (j == 0) { idxb[i * 4 + r] = redi[0]; sc[redi[0]] = -1e300; }
    __syncthreads();
  }
}

__global__ void edge_k(const float* __restrict__ xg, const int* __restrict__ idxb, float* __restrict__ edge){
  size_t idx = (size_t)blockIdx.x * 256 + threadIdx.x;
  int i = (int)(idx >> 9), c = (int)(idx & 511);
  const int* id = idxb + i * 4;
  edge[idx] = 0.25f * (xg[(size_t)id[0]*512 + c] + xg[(size_t)id[1]*512 + c] +
                       xg[(size_t)id[2]*512 + c] + xg[(size_t)id[3]*512 + c]);
}
__global__ void h1gather_k(const float* __restrict__ h1, const int* __restrict__ idxb, float* __restrict__ out){
  size_t idx = (size_t)blockIdx.x * 256 + threadIdx.x;
  int i = (int)(idx >> 9), c = (int)(idx & 511);
  const int* id = idxb + i * 4;
  out[idx] = h1[idx] + 0.25f * (h1[(size_t)id[0]*512 + c] + h1[(size_t)id[1]*512 + c] +
                                h1[(size_t)id[2]*512 + c] + h1[(size_t)id[3]*512 + c]);
}
__global__ void vadd_k(const float* __restrict__ a, const float* __restrict__ b, float* __restrict__ c){
  size_t idx = (size_t)blockIdx.x * 256 + threadIdx.x;
  c[idx] = a[idx] + b[idx];
}

__global__ void logits2(const float* __restrict__ src, const float* __restrict__ w,
                        const float* __restrict__ bias, float* __restrict__ out){
  int rc = blockIdx.x; int r = rc >> 1, c = rc & 1;
  int t = threadIdx.x; // 64
  double s = 0.;
  for (int k = t; k < 512; k += 64) s += (double)src[(size_t)r * 512 + k] * (double)w[(size_t)c * 512 + k];
  for (int off = 32; off > 0; off >>= 1) s += __shfl_down(s, off);
  if (t == 0) out[rc] = (float)(s + (double)bias[c]);
}

__global__ void sentinel_k(float* out){ if (threadIdx.x < 12) out[threadIdx.x] = 1e30f; }

// ---------------- host-side nystrom block ----------------
struct NysBufs {
  float *pad, *qkv, *ql, *kl, *klT, *av, *zav, *merged;
  float *a2, *zA, *zB, *az, *t1, *t2, *scal, *accp, *mlp;
};

static void run_nystrom(hipStream_t stream, float* hbuf,
                        const float* lng, const float* lnb, const float* qkvw,
                        const float* outw, const float* outb, const float* rk,
                        const NysBufs& w)
{
  ln_pad<<<BB * NPAD, 256, 0, stream>>>(hbuf, w.pad, lng, lnb);
  gemm_f32<<<dim3(NT/128, (BB*NPAD)/128), 256, 0, stream>>>(w.pad, qkvw, nullptr, nullptr, w.qkv,
                                                            BB*NPAD, NT, DIM, 0);
  // pad dead; a2/zA/zB/az overlay it.
  landmark<<<BB * NH * LM, 64, 0, stream>>>(w.qkv, w.ql, w.kl);
  transpose_kl<<<dim3(LM/64, 16), 256, 0, stream>>>(w.kl, w.klT);
  a2_kernel<<<BB * NH * LM, 256, 0, stream>>>(w.ql, w.klT, w.a2);
  colrow_max<<<16, 256, 0, stream>>>(w.a2, w.scal);
  scal_red<<<1, 64, 0, stream>>>(w.scal);
  z0_kernel<<<4096, 256, 0, stream>>>(w.a2, w.zA, w.scal);
  fa3v_kernel<<<dim3(4, 4, 16), 256, 0, stream>>>(w.qkv, w.ql, w.accp, w.mlp);
  fa3v_combine<<<64, 256, 0, stream>>>(w.accp, w.mlp, w.av);
  float* zc = w.zA; float* zn = w.zB;
  for (int it = 0; it < 6; ++it) {
    mm_bf<<<dim3(4,4,16), 256, 0, stream>>>(w.a2, zc, w.az, w.t1, 256, 1.f, 0.f, 7.f);
    mm_bf<<<dim3(4,4,16), 256, 0, stream>>>(w.az, w.t1, w.t2, nullptr, 256, -1.f, 15.f, 0.f);
    mm_bf<<<dim3(4,4,16), 256, 0, stream>>>(w.az, w.t2, w.t1, nullptr, 256, -1.f, 13.f, 0.f);
    mm_bf<<<dim3(4,4,16), 256, 0, stream>>>(zc, w.t1, zn, nullptr, 256, 0.25f, 0.f, 0.f);
    float* tmp = zc; zc = zn; zn = tmp;
  }
  mm_bf<<<dim3(1,4,16), 256, 0, stream>>>(zc, w.av, w.zav, nullptr, 64, 1.f, 0.f, 0.f);
  // t1/t2 dead; conv_res reinitializes merged.
  conv_res<<<(BB * NPAD * DIM) / 256, 256, 0, stream>>>(w.qkv, rk, w.merged);
  fa1_kernel<<<dim3(NPAD/64, 16), 256, 0, stream>>>(w.qkv, w.kl, w.zav, w.merged);
  for (int b = 0; b < BB; ++b)
    gemm_f32<<<dim3(DIM/128, (N1+127)/128), 256, 0, stream>>>(w.merged + ((size_t)b*NPAD + PADR)*DIM,
                                                              outw, outb,
                                                              hbuf + (size_t)b*N1*DIM,
                                                              hbuf + (size_t)b*N1*DIM,
                                                              N1, DIM, DIM, 0);
}

extern "C" void kernel_launch(void* const* d_in, const int* in_sizes, int n_in,
                              void* d_out, int out_size, void* d_ws, size_t ws_size,
                              hipStream_t stream) {
  (void)in_sizes; (void)n_in; (void)out_size;
  const float* x        = (const float*)d_in[0];
  const float* fc1_w    = (const float*)d_in[1];
  const float* fc1_b    = (const float*)d_in[2];
  const float* cls_tok  = (const float*)d_in[3];
  const float* ln1_g    = (const float*)d_in[4];
  const float* ln1_b    = (const float*)d_in[5];
  const float* qkv1_w   = (const float*)d_in[6];
  const float* out1_w   = (const float*)d_in[7];
  const float* out1_b   = (const float*)d_in[8];
  const float* res1_k   = (const float*)d_in[9];
  const float* ppeg_w7  = (const float*)d_in[10];
  const float* ppeg_b7  = (const float*)d_in[11];
  const float* ppeg_w5  = (const float*)d_in[12];
  const float* ppeg_b5  = (const float*)d_in[13];
  const float* ppeg_w3  = (const float*)d_in[14];
  const float* ppeg_b3  = (const float*)d_in[15];
  const float* ln2_g    = (const float*)d_in[16];
  const float* ln2_b    = (const float*)d_in[17];
  const float* qkv2_w   = (const float*)d_in[18];
  const float* out2_w   = (const float*)d_in[19];
  const float* out2_b   = (const float*)d_in[20];
  const float* res2_k   = (const float*)d_in[21];
  const float* norm_g   = (const float*)d_in[22];
  const float* norm_b   = (const float*)d_in[23];
  const float* fc2_w    = (const float*)d_in[24];
  const float* fc2_b    = (const float*)d_in[25];
  const float* dsl_w1   = (const float*)d_in[26];
  const float* dsl_b1   = (const float*)d_in[27];
  const float* dsl_w2   = (const float*)d_in[28];
  const float* dsl_b2   = (const float*)d_in[29];
  const float* gcn_w1   = (const float*)d_in[30];
  const float* gcn_we   = (const float*)d_in[31];
  const float* gcn_b1   = (const float*)d_in[32];
  const float* gcn_w2   = (const float*)d_in[33];
  const float* gcn_b2   = (const float*)d_in[34];
  const float* gcn_hw   = (const float*)d_in[35];
  const float* gcn_hb   = (const float*)d_in[36];
  const float* gcn_dw   = (const float*)d_in[37];
  const float* gcn_db   = (const float*)d_in[38];
  const float* rehearsal= (const float*)d_in[39];
  float* out = (float*)d_out;

  char* base = (char*)d_ws;
  size_t off = 0;
  auto takeb = [&](size_t bytes) { void* p = base + off; off += (bytes + 255) & ~(size_t)255; return p; };

  float* h    = (float*)takeb((size_t)BB * N1 * DIM * 4);
  float* h2   = (float*)takeb((size_t)BB * N1 * DIM * 4);
  NysBufs nb;
  nb.pad    = (float*)takeb((size_t)BB * NPAD * DIM * 4);     // 17.8 MB; a2/zA/zB/az overlay
  nb.qkv    = (float*)takeb((size_t)BB * NPAD * NT * 4);
  nb.ql     = (float*)takeb((size_t)BB * NH * LM * DH * 4);
  nb.kl     = (float*)takeb((size_t)BB * NH * LM * DH * 4);
  nb.klT    = (float*)takeb((size_t)BB * NH * LM * DH * 4);
  nb.av     = (float*)takeb((size_t)BB * NH * LM * DH * 4);
  nb.zav    = (float*)takeb((size_t)BB * NH * LM * DH * 4);
  nb.merged = (float*)takeb((size_t)BB * NPAD * DIM * 4);     // 17.8 MB; t1/t2 overlay
  nb.scal   = (float*)takeb(64 * 4);
  nb.accp   = (float*)takeb((size_t)256 * 4096 * 4);          // 4.2 MB partial acc
  nb.mlp    = (float*)takeb((size_t)256 * 128 * 4);
  float* hcls = (float*)takeb((size_t)BB * DIM * 4);
  float* xc   = (float*)takeb((size_t)256 * 512 * 4);
  float* xg1  = (float*)takeb((size_t)256 * 256 * 4);
  float* xg   = (float*)takeb((size_t)256 * 512 * 4);
  double* rn  = (double*)takeb(256 * 8);
  int*   idxb = (int*)takeb(1024 * 4);
  float* edge = (float*)takeb((size_t)256 * 512 * 4);
  float* h1g  = (float*)takeb((size_t)256 * 512 * 4);
  float* h1pn = (float*)takeb((size_t)256 * 512 * 4);
  float* h2g  = (float*)takeb((size_t)256 * 512 * 4);

  const size_t MAT = (size_t)16 * 65536;      // 1M floats = 4 MB
  nb.a2 = nb.pad;
  nb.zA = nb.pad + MAT;
  nb.zB = nb.pad + 2 * MAT;
  nb.az = nb.pad + 3 * MAT;                    // 16 MB <= pad's 17.8 MB
  nb.t1 = nb.merged;
  nb.t2 = nb.merged + MAT;

  if (ws_size < off) { sentinel_k<<<1, 64, 0, stream>>>(out); return; }

  // --- stage A: fc1 + cls ---
  set_cls<<<1, 1024, 0, stream>>>(h, cls_tok);
  for (int b = 0; b < BB; ++b)
    gemm_f32<<<dim3(DIM/128, NSEQ/128), 256, 0, stream>>>(x + (size_t)b*NSEQ*DIM, fc1_w, fc1_b, nullptr,
                                                          h + ((size_t)b*N1 + 1)*DIM, NSEQ, DIM, DIM, 1);
  // --- nystrom block 1 (residual into h) ---
  run_nystrom(stream, h, ln1_g, ln1_b, qkv1_w, out1_w, out1_b, res1_k, nb);

  // --- PPEG ---
  copy_cls<<<1, 1024, 0, stream>>>(h2, h);
  dwconv<<<(BB * NSEQ * DIM) / 256, 256, 0, stream>>>(h, ppeg_w7, ppeg_b7, ppeg_w5, ppeg_b5,
                                                      ppeg_w3, ppeg_b3, h2);
  // --- nystrom block 2 (residual into h2) ---
  run_nystrom(stream, h2, ln2_g, ln2_b, qkv2_w, out2_w, out2_b, res2_k, nb);

  // --- final LN (row 0) + heads ---
  final_ln<<<BB, 256, 0, stream>>>(h2, norm_g, norm_b, hcls);
  logits2<<<4, 64, 0, stream>>>(hcls, fc2_w, fc2_b, out + 0);

  // --- GCN branch ---
  build_xc<<<512, 256, 0, stream>>>(hcls, rehearsal, xc);
  gemm_f32<<<dim3(256/128, 2), 256, 0, stream>>>(xc, dsl_w1, dsl_b1, nullptr, xg1, 256, 256, 512, 2);
  gemm_f32<<<dim3(512/128, 2), 256, 0, stream>>>(xg1, dsl_w2, dsl_b2, nullptr, xg, 256, 512, 256, 2);
  norms_k<<<256, 256, 0, stream>>>(xg, rn);
  topk_k<<<256, 256, 0, stream>>>(xg, rn, idxb);
  edge_k<<<512, 256, 0, stream>>>(xg, idxb, edge);
  vadd_k<<<512, 256, 0, stream>>>(xg, edge, h1pn);
  gemm_f32<<<dim3(512/128, 2), 256, 0, stream>>>(h1pn, gcn_w1, nullptr, nullptr, h1g, 256, 512, 512, 0);
  gemm_f32<<<dim3(512/128, 2), 256, 0, stream>>>(edge, gcn_we, gcn_b1, h1g, h1g, 256, 512, 512, 1);
  h1gather_k<<<512, 256, 0, stream>>>(h1g, idxb, h1pn);
  gemm_f32<<<dim3(512/128, 2), 256, 0, stream>>>(h1pn, gcn_w2, gcn_b2, nullptr, h2g, 256, 512, 512, 0);
  logits2<<<4, 64, 0, stream>>>(h2g, gcn_hw, gcn_hb, out + 4);
  logits2<<<4, 64, 0, stream>>>(h1g, gcn_dw, gcn_db, out + 8);
}